// Round 11
// baseline (176.335 us; speedup 1.0000x reference)
//
#include <hip/hip_runtime.h>

#define DI __device__ __forceinline__

typedef __bf16 bf16_t;
typedef __bf16 bf16x4 __attribute__((ext_vector_type(4)));
typedef __bf16 bf16x8 __attribute__((ext_vector_type(8)));
typedef float f32x4 __attribute__((ext_vector_type(4)));
typedef unsigned long long u64;

// Problem constants
// B=64, N=512, F=64, H=128, FO=64, K=16

DI bf16_t f2b(float f) {
  unsigned u = __float_as_uint(f);
  unsigned r = (u + 0x7fffu + ((u >> 16) & 1u)) >> 16;
  return __builtin_bit_cast(bf16_t, (unsigned short)r);
}
DI float b2f(bf16_t h) {
  return __uint_as_float(((unsigned)__builtin_bit_cast(unsigned short, h)) << 16);
}
DI f32x4 zero4() { f32x4 z = {0.f, 0.f, 0.f, 0.f}; return z; }

DI bf16x8 make_frag(const float* p, bool wantlo) {
  float4 v0 = *(const float4*)p;
  float4 v1 = *(const float4*)(p + 4);
  float vv[8] = {v0.x, v0.y, v0.z, v0.w, v1.x, v1.y, v1.z, v1.w};
  bf16x8 a;
#pragma unroll
  for (int j = 0; j < 8; ++j) {
    bf16_t hi = f2b(vv[j]);
    a[j] = wantlo ? f2b(vv[j] - b2f(hi)) : hi;
  }
  return a;
}
// Both planes from one load (dedup for knode L1).
DI void make_frag2(const float* p, bf16x8* hi, bf16x8* lo) {
  float4 v0 = *(const float4*)p;
  float4 v1 = *(const float4*)(p + 4);
  float vv[8] = {v0.x, v0.y, v0.z, v0.w, v1.x, v1.y, v1.z, v1.w};
#pragma unroll
  for (int j = 0; j < 8; ++j) {
    bf16_t h = f2b(vv[j]);
    (*hi)[j] = h;
    (*lo)[j] = f2b(vv[j] - b2f(h));
  }
}

DI u64 u64min(u64 a, u64 b) { return a < b ? a : b; }
// ctrl must be an ICE for __builtin_amdgcn_update_dpp -> template parameter.
template <int CTRL>
DI u64 dpp_u64(u64 v) {
  int lo = (int)(unsigned)(v & 0xffffffffull);
  int hi = (int)(unsigned)(v >> 32);
  int tlo = __builtin_amdgcn_update_dpp(0, lo, CTRL, 0xF, 0xF, true);
  int thi = __builtin_amdgcn_update_dpp(0, hi, CTRL, 0xF, 0xF, true);
  return (((u64)(unsigned)thi) << 32) | (unsigned)tlo;
}
template <int CTRL>
DI float dpp_f32(float v) {
  int t = __builtin_amdgcn_update_dpp(0, (int)__float_as_uint(v), CTRL, 0xF, 0xF, true);
  return __uint_as_float((unsigned)t);
}
// Min over each 16-lane row; result uniform within the row.
DI u64 rowmin_u64(u64 v) {
  v = u64min(v, dpp_u64<0xB1>(v));
  v = u64min(v, dpp_u64<0x4E>(v));
  v = u64min(v, dpp_u64<0x141>(v));
  v = u64min(v, dpp_u64<0x140>(v));
  return v;
}
// Sum over each 16-lane row (butterfly); result uniform within the row.
DI float rowsum_f32(float v) {
  v += dpp_f32<0xB1>(v);
  v += dpp_f32<0x4E>(v);
  v += dpp_f32<0x141>(v);
  v += dpp_f32<0x140>(v);
  return v;
}
// Bitonic sort, 16 elements, ascending. 80 CAS, all indices compile-time.
DI void bitonic16(u64* a) {
#pragma unroll
  for (int k = 2; k <= 16; k <<= 1)
#pragma unroll
    for (int j = k >> 1; j > 0; j >>= 1)
#pragma unroll
      for (int i = 0; i < 16; ++i) {
        const int l = i ^ j;
        if (l > i) {
          const bool up = ((i & k) == 0);
          const bool sw = up ? (a[i] > a[l]) : (a[i] < a[l]);
          const u64 t0 = a[i], t1 = a[l];
          a[i] = sw ? t1 : t0;
          a[l] = sw ? t0 : t1;
        }
      }
}
// Insert k into ascending sorted a[16], dropping the max. INF insert = no-op.
DI void sorted_insert16(u64* a, u64 k) {
  u64 na[16];
#pragma unroll
  for (int p = 0; p < 16; ++p) {
    const bool cur_gt = (a[p] > k);
    const bool prv_le = (p == 0) ? true : (a[p - 1] <= k);
    na[p] = !cur_gt ? a[p] : (prv_le ? k : a[p - 1]);
  }
#pragma unroll
  for (int p = 0; p < 16; ++p) a[p] = na[p];
}

// ---------------- Kernel F: fused prep — xplanes (512) + compact (64) + pack (64) --
__global__ void __launch_bounds__(256) kfuse(const float* __restrict__ nodes,
    const int* __restrict__ mask,
    const float* __restrict__ We1, const float* __restrict__ We2,
    const float* __restrict__ Wn1, const float* __restrict__ Wn2,
    float* __restrict__ x, bf16_t* __restrict__ xhi, bf16_t* __restrict__ xlo,
    float* __restrict__ sq, int* __restrict__ vlist, int* __restrict__ vcnt,
    bf16_t* __restrict__ W1p, bf16_t* __restrict__ W2p,
    bf16_t* __restrict__ Wn1p, bf16_t* __restrict__ Wn2p) {
  const int blk = blockIdx.x, t = threadIdx.x;
  __shared__ int cnts[8];
  __shared__ int basep[8];

  if (blk < 512) {
    // ---- xplanes: batch b, nodes n0..n0+63; 16 threads per row ----
    const int b = blk >> 3, n0 = (blk & 7) * 64;
#pragma unroll
    for (int i = 0; i < 4; ++i) {
      const int idx = t + 256 * i;
      const int gi = b * 512 + n0 + (idx >> 4);
      const int fo = (idx & 15) * 4;
      const float fm = (float)mask[gi];
      const size_t ro = (size_t)gi * 64;
      float4 v = *(const float4*)(nodes + ro + fo);
      v.x *= fm; v.y *= fm; v.z *= fm; v.w *= fm;
      *(float4*)(x + ro + fo) = v;
      float vv[4] = {v.x, v.y, v.z, v.w};
      bf16x4 hh, ll;
#pragma unroll
      for (int k = 0; k < 4; ++k) {
        bf16_t hi = f2b(vv[k]);
        hh[k] = hi;
        ll[k] = f2b(vv[k] - b2f(hi));
      }
      *(bf16x4*)(xhi + ro + fo) = hh;
      *(bf16x4*)(xlo + ro + fo) = ll;
      float s = v.x * v.x + v.y * v.y + v.z * v.z + v.w * v.w;
      s = rowsum_f32(s);  // sum over the row's 16 lanes (uniform in row)
      if ((t & 15) == 0) sq[gi] = s;
    }
  } else if (blk < 576) {
    // ---- compaction: one block per batch ----
    const int b = blk - 512, lane = t & 63, w = t >> 6;
    unsigned long long bal[2]; int flag[2];
#pragma unroll
    for (int h = 0; h < 2; ++h) {
      flag[h] = (mask[b * 512 + h * 256 + t] != 0);
      bal[h] = __ballot(flag[h]);
      if (lane == 0) cnts[h * 4 + w] = __popcll(bal[h]);
    }
    __syncthreads();
    if (t == 0) {
      int a = 0;
      for (int c = 0; c < 8; ++c) { basep[c] = a; a += cnts[c]; }
      vcnt[b] = a;
    }
    __syncthreads();
#pragma unroll
    for (int h = 0; h < 2; ++h) {
      if (flag[h]) {
        const unsigned long long lt = (lane == 0) ? 0ull : (~0ull >> (64 - lane));
        const int pos = basep[h * 4 + w] + __popcll(bal[h] & lt);
        vlist[b * 512 + pos] = h * 256 + t;
      }
    }
  } else {
    // ---- weight pack ----
    int p = (blk - 576) * 256 + t;  // 0..16383
    const float* W; bf16_t* dst; int K, Nn, local, mode;
    if (p < 4096)       { W = We1; dst = W1p;  K = 128; Nn = 128; mode = 0; local = p; }
    else if (p < 8192)  { W = We2; dst = W2p;  K = 128; Nn = 128; mode = 1; local = p - 4096; }
    else if (p < 14336) { W = Wn1; dst = Wn1p; K = 192; Nn = 128; mode = 0; local = p - 8192; }
    else                { W = Wn2; dst = Wn2p; K = 128; Nn = 64;  mode = 1; local = p - 14336; }
    int lane = local & 63;
    int nnt = (Nn >> 4);
    int chunk = local >> 6;
    int nt = chunk % nnt;
    int s = chunk / nnt;
    int n = nt * 16 + (lane & 15);
    int kbase = s * 32 + ((lane >> 4) * 8);
    bf16x8 v;
#pragma unroll
    for (int j = 0; j < 8; ++j) {
      int kp = kbase + j;
      int region = kp / K;
      int kk = kp - region * K;
      float w = W[kk * Nn + n];
      bf16_t hi = f2b(w);
      v[j] = (mode == 1 && region == 1) ? f2b(w - b2f(hi)) : hi;
    }
    *(bf16x8*)(dst + (size_t)local * 8) = v;
  }
}

// ---------------- Kernel B: distances + top-16 — MFMA Gram, 4-deep B pipeline -----
__global__ void __launch_bounds__(256) kknn(const bf16_t* __restrict__ xhi,
    const bf16_t* __restrict__ xlo,
    const float* __restrict__ sq, const int* __restrict__ vlist,
    const int* __restrict__ vcnt, int* __restrict__ idxg) {
  const int b = blockIdx.x & 63, tile = blockIdx.x >> 6;
  const int nv = vcnt[b];
  if (tile * 16 >= nv) return;  // block-uniform, before any barrier
  const int t = threadIdx.x, lane = t & 63, w = t >> 6;
  const int i = lane >> 4, d = lane & 15;   // i: k-group / C-row group; d: C-col
  __shared__ float sqs[512];
  __shared__ int vls[512];
  __shared__ __align__(16) float S[16 * 520];   // 33.3 KB Gram tile (row stride 520)
  for (int k = t; k < 512; k += 256) { sqs[k] = sq[b * 512 + k]; vls[k] = vlist[b * 512 + k]; }
  __syncthreads();

  const size_t xb = (size_t)b * 512 * 64;

  // ---- A fragments: 16 receiver rows of this tile (A row m = d = lane&15) ----
  const int aslot = tile * 16 + d;
  const int arow = vls[aslot < nv ? aslot : 0];
  bf16x8 ah[2], al[2];
#pragma unroll
  for (int kh = 0; kh < 2; ++kh) {
    ah[kh] = *(const bf16x8*)(xhi + xb + (size_t)arow * 64 + kh * 32 + i * 8);
    al[kh] = *(const bf16x8*)(xlo + xb + (size_t)arow * 64 + kh * 32 + i * 8);
  }

  // receiver identity for selection (thread handles recv w*4+i)
  const int rslot = tile * 16 + w * 4 + i;
  const bool vrow = (rslot < nv);
  const int nrow = vls[rslot < nv ? rslot : 0];
  const float sqn = sqs[nrow];

  // ---- candidate row ids for this wave's tiles (ct = w + 4*jj) ----
  int crs[8];
#pragma unroll
  for (int jj = 0; jj < 8; ++jj) {
    const int c = (w + 4 * jj) * 16 + d;
    crs[jj] = vls[c < nv ? c : 0];
  }

  // ---- Gram tiles: 4-deep rolling B-frag pipeline, C -> LDS ----
  bf16x8 pbh[4][2], pbl[4][2];
#pragma unroll
  for (int jj = 0; jj < 4; ++jj) {
    if ((w + 4 * jj) * 16 < nv) {  // wave-uniform
#pragma unroll
      for (int kh = 0; kh < 2; ++kh) {
        pbh[jj][kh] = *(const bf16x8*)(xhi + xb + (size_t)crs[jj] * 64 + kh * 32 + i * 8);
        pbl[jj][kh] = *(const bf16x8*)(xlo + xb + (size_t)crs[jj] * 64 + kh * 32 + i * 8);
      }
    }
  }
#pragma unroll
  for (int jj = 0; jj < 8; ++jj) {
    const int ct = w + 4 * jj;
    if (ct * 16 < nv) {  // wave-uniform
      const int sl = jj & 3;  // compile-time (unrolled)
      // copy out, then refill the slot with tile jj+4 (loads issue before MFMAs)
      bf16x8 bh[2] = {pbh[sl][0], pbh[sl][1]};
      bf16x8 bl[2] = {pbl[sl][0], pbl[sl][1]};
      if (jj < 4 && (w + 4 * (jj + 4)) * 16 < nv) {
#pragma unroll
        for (int kh = 0; kh < 2; ++kh) {
          pbh[sl][kh] = *(const bf16x8*)(xhi + xb + (size_t)crs[jj + 4] * 64 + kh * 32 + i * 8);
          pbl[sl][kh] = *(const bf16x8*)(xlo + xb + (size_t)crs[jj + 4] * 64 + kh * 32 + i * 8);
        }
      }
      f32x4 acc = zero4();
#pragma unroll
      for (int kh = 0; kh < 2; ++kh) {
        acc = __builtin_amdgcn_mfma_f32_16x16x32_bf16(ah[kh], bh[kh], acc, 0, 0, 0);
        acc = __builtin_amdgcn_mfma_f32_16x16x32_bf16(ah[kh], bl[kh], acc, 0, 0, 0);
        acc = __builtin_amdgcn_mfma_f32_16x16x32_bf16(al[kh], bh[kh], acc, 0, 0, 0);
        acc = __builtin_amdgcn_mfma_f32_16x16x32_bf16(al[kh], bl[kh], acc, 0, 0, 0);
      }
      // D(m=recv=i*4+r, n=cand=d): S[recv][cand]
#pragma unroll
      for (int r = 0; r < 4; ++r) S[(i * 4 + r) * 520 + ct * 16 + d] = acc[r];
    }
  }
  __syncthreads();

  // ---- key build: first 16 j-groups -> s1; sort; overflow groups insert ----
  const u64 INF64 = ~0ull;
  u64 s1[16];
#pragma unroll
  for (int j = 0; j < 16; ++j) s1[j] = INF64;
#pragma unroll
  for (int j = 0; j < 16; ++j) {
    if (j * 16 < nv) {  // uniform
      const int c = j * 16 + d;
      const int m = vls[c < nv ? c : 0];
      const float dot = S[(w * 4 + i) * 520 + j * 16 + d];
      const float dd = fabsf(sqn + sqs[m] - 2.f * dot);
      const u64 key = (((u64)__float_as_uint(dd)) << 32) | (unsigned)m;
      const bool ok = (c < nv) && (m != nrow);
      s1[j] = ok ? key : INF64;
    }
  }
  bitonic16(s1);
  // overflow: slots 256.. (wave-uniform trip count, ~0-3 iterations typical)
  for (int j = 16; j * 16 < nv; ++j) {
    const int c = j * 16 + d;
    const int m = vls[c < nv ? c : 0];
    const float dot = S[(w * 4 + i) * 520 + j * 16 + d];
    const float dd = fabsf(sqn + sqs[m] - 2.f * dot);
    const u64 key = (((u64)__float_as_uint(dd)) << 32) | (unsigned)m;
    const bool ok = (c < nv) && (m != nrow);
    sorted_insert16(s1, ok ? key : INF64);
  }

  // ---- extraction: 16 rounds, single array ----
  int res = nrow;
#pragma unroll
  for (int ts = 0; ts < 16; ++ts) {
    const u64 wmin = rowmin_u64(s1[0]);
    if (d == ts) res = (wmin == INF64) ? nrow : (int)(unsigned)(wmin & 0xffffffffull);
    const bool w1 = (wmin != INF64) && (s1[0] == wmin);
#pragma unroll
    for (int k = 0; k < 15; ++k) s1[k] = w1 ? s1[k + 1] : s1[k];
    s1[15] = w1 ? INF64 : s1[15];
  }
  // SLOT-indexed store
  if (vrow) idxg[((size_t)b * 512 + rslot) * 16 + d] = res;
}

// ---------------- Kernel C: edge MLP — LDS diet: 40 KB -> 4 blocks/CU -------------
// r9 (LDS-BW dedup) and r10 (gather prefetch) were both NEUTRAL -> kedge is
// OCCUPANCY-bound: 2 waves/SIMD can't overlap MFMA/VALU/gather phases
// (MfmaUtil 21 + VALUBusy 21, Occ 14%). Diet:
//  * W2 read from GLOBAL (L2-resident 32 KB, coalesced 512B/wave) -> wbuf 32 KB.
//  * hfrag quarter-H (one slab per step; slab order 0,1,2,3 unchanged -> FP
//    bit-identical) -> 8 KB.
//  * LDS = 40 KB exactly -> 4 blocks/CU (160 KB) = 4 waves/SIMD, 2x TLP.
//  * r10 naf double-buffer dropped (neutral; keeps VGPR <= 128 for 4 waves/SIMD).
__global__ void __launch_bounds__(256, 2) kedge(const bf16_t* __restrict__ xhi,
    const bf16_t* __restrict__ xlo, const int* __restrict__ idxg,
    const int* __restrict__ vlist, const int* __restrict__ vcnt,
    const bf16_t* __restrict__ W1p, const bf16_t* __restrict__ W2p,
    const float* __restrict__ be1, const float* __restrict__ be2,
    float* __restrict__ pooled) {
  __shared__ __align__(16) bf16_t wbuf[16384];      // 32 KB: W1 slabs 0-3 only
  __shared__ __align__(16) bf16_t hfrag[4][2][512]; // 8 KB (one slab per u per wave)
  const int t = threadIdx.x, lane = t & 63, w = t >> 6;
  const int q = lane >> 4, e = lane & 15;
  const int bb = blockIdx.x & 63;              // same-XCD batch grouping
  const int s0 = ((blockIdx.x >> 6) * 4 + w) * 2;  // even slot base 0..62

  // ---- stage W1 once: 32 KB, 8 uint4 per thread ----
  {
    const uint4* s1 = (const uint4*)W1p;
    uint4* dst = (uint4*)wbuf;
#pragma unroll
    for (int i = 0; i < 8; ++i) dst[t + 256 * i] = s1[t + 256 * i];
  }
  __syncthreads();  // the ONLY barrier in this kernel

  const int nv = vcnt[bb];
  if (s0 >= nv) return;

  // slot-pair loader: vlist value (wave-uniform) + 16 neighbor ids (slot-indexed idxg)
  int vl[2], sv[2];
#pragma unroll
  for (int u = 0; u < 2; ++u) {
    const int sl = (s0 + u) < nv ? (s0 + u) : 0;
    vl[u] = vlist[bb * 512 + sl];
    sv[u] = idxg[((size_t)(bb * 512 + sl) << 4) + e];
  }

  for (int base = s0; base < nv; base += 64) {
    const bool act1 = (base + 1) < nv;
    const int gid0 = bb * 512 + vl[0];
    const int gid1 = bb * 512 + vl[1];
    const size_t rb0 = (size_t)gid0 << 6;
    const size_t rb1 = (size_t)gid1 << 6;
    const size_t nb0 = (size_t)(bb * 512 + sv[0]) << 6;
    const size_t nb1 = (size_t)(bb * 512 + sv[1]) << 6;

    // ---- issue all 16 A-fragment loads for this slot pair ----
    // af[u][k] k<4: receiver (ph0), k>=4: neighbors (ph1); (k&1)=inner, (k>>1)&1=lo
    bf16x8 af[2][8];
#pragma unroll
    for (int k = 0; k < 4; ++k) {
      const int off = (k & 1) * 32 + q * 8;
      const bf16_t* pl = (k >> 1) ? xlo : xhi;
      af[0][k]     = *(const bf16x8*)(pl + rb0 + off);
      af[1][k]     = *(const bf16x8*)(pl + rb1 + off);
      af[0][4 + k] = *(const bf16x8*)(pl + nb0 + off);
      af[1][4 + k] = *(const bf16x8*)(pl + nb1 + off);
    }

    // ---- prefetch next slot pair's indices (1-deep) ----
    int nvl[2] = {vl[0], vl[1]}, nsv[2] = {sv[0], sv[1]};
    {
      const int nb = base + 64;
      if (nb < nv) {
#pragma unroll
        for (int u = 0; u < 2; ++u) {
          const int sl = (nb + u) < nv ? (nb + u) : 0;
          nvl[u] = vlist[bb * 512 + sl];
          nsv[u] = idxg[((size_t)(bb * 512 + sl) << 4) + e];
        }
      }
    }

    // ---- Layer 1: slab-dedup — one bfv read feeds hi+lo for both u ----
    f32x4 acc[2][8];
#pragma unroll
    for (int u = 0; u < 2; ++u)
#pragma unroll
      for (int nt = 0; nt < 8; ++nt) acc[u][nt] = zero4();

#pragma unroll
    for (int ph = 0; ph < 2; ++ph)
#pragma unroll
      for (int inner = 0; inner < 2; ++inner) {
        const bf16_t* wb = wbuf + (ph * 2 + inner) * 4096;
        const bf16x8 h0 = af[0][ph * 4 + inner];
        const bf16x8 h1 = af[1][ph * 4 + inner];
        const bf16x8 l0 = af[0][ph * 4 + 2 + inner];
        const bf16x8 l1 = af[1][ph * 4 + 2 + inner];
#pragma unroll
        for (int nt = 0; nt < 8; ++nt) {
          const bf16x8 bfv = *(const bf16x8*)(wb + (nt * 64 + lane) * 8);
          acc[0][nt] = __builtin_amdgcn_mfma_f32_16x16x32_bf16(h0, bfv, acc[0][nt], 0, 0, 0);
          acc[0][nt] = __builtin_amdgcn_mfma_f32_16x16x32_bf16(l0, bfv, acc[0][nt], 0, 0, 0);
          acc[1][nt] = __builtin_amdgcn_mfma_f32_16x16x32_bf16(h1, bfv, acc[1][nt], 0, 0, 0);
          acc[1][nt] = __builtin_amdgcn_mfma_f32_16x16x32_bf16(l1, bfv, acc[1][nt], 0, 0, 0);
        }
      }

    // ---- L2 in four slab-quarters interleaved with epilogue-1 (slab order 0..3,
    //      same accumulation order as before -> FP identical). W2 from GLOBAL. ----
    f32x4 acc2[2][8];
#pragma unroll
    for (int u = 0; u < 2; ++u)
#pragma unroll
      for (int nt = 0; nt < 8; ++nt) acc2[u][nt] = zero4();

#pragma unroll
    for (int qq = 0; qq < 4; ++qq) {
      // epilogue-1 quarter: features of slab qq (nt = qq*2, qq*2+1)
#pragma unroll
      for (int u = 0; u < 2; ++u)
#pragma unroll
        for (int nt2 = 0; nt2 < 2; ++nt2) {
          const int nt = qq * 2 + nt2;
          const int cc = nt * 16 + e;
          const float bv = be1[cc];
          const int bse = (q * 4 + 16 * ((cc >> 3) & 3)) * 8 + (cc & 7);
#pragma unroll
          for (int r = 0; r < 4; ++r)
            hfrag[w][u][bse + r * 8] = f2b(fmaxf(acc[u][nt][r] + bv, 0.f));
        }
      // L2 quarter: W2 hi slab qq, read straight from global (L2-resident)
      {
        const bf16x8 a20 = *(const bf16x8*)(&hfrag[w][0][lane * 8]);
        const bf16x8 a21 = *(const bf16x8*)(&hfrag[w][1][lane * 8]);
        const bf16_t* wb2 = W2p + qq * 4096;
#pragma unroll
        for (int nt = 0; nt < 8; ++nt) {
          const bf16x8 bfv = *(const bf16x8*)(wb2 + (nt * 64 + lane) * 8);
          acc2[0][nt] = __builtin_amdgcn_mfma_f32_16x16x32_bf16(a20, bfv, acc2[0][nt], 0, 0, 0);
          acc2[1][nt] = __builtin_amdgcn_mfma_f32_16x16x32_bf16(a21, bfv, acc2[1][nt], 0, 0, 0);
        }
      }
    }

    // ---- Epilogue 2: bias+relu, mean over 16 edges (cnt==16 exactly) ----
#pragma unroll
    for (int u = 0; u < 2; ++u) {
      if (u == 0 || act1) {
        const int gid = u ? gid1 : gid0;
#pragma unroll
        for (int nt = 0; nt < 8; ++nt) {
          const float bv = be2[nt * 16 + e];
          float part = 0.f;
#pragma unroll
          for (int r = 0; r < 4; ++r) part += fmaxf(acc2[u][nt][r] + bv, 0.f);
          part += __shfl_xor(part, 16, 64);
          part += __shfl_xor(part, 32, 64);
          if (lane < 16) pooled[(size_t)gid * 128 + nt * 16 + lane] = part * 0.0625f;
        }
      }
    }

    vl[0] = nvl[0]; vl[1] = nvl[1];
    sv[0] = nsv[0]; sv[1] = nsv[1];
  }
}

// ---------------- Kernel D: node MLP — persistent-weight + slab-dedup L1 ----------
__global__ void __launch_bounds__(256, 2) knode(const float* __restrict__ x,
    const float* __restrict__ pooled, const int* __restrict__ mask,
    const bf16_t* __restrict__ Wn1p, const bf16_t* __restrict__ Wn2p,
    const float* __restrict__ bn1, const float* __restrict__ bn2,
    float* __restrict__ out) {
  __shared__ __align__(16) bf16_t wbuf[32768];     // 64 KB: Wn1 slabs0-5 | Wn2 slabs0-3
  __shared__ __align__(16) bf16_t hfrag[4][1024];  // 8 KB (half-H per wave)
  const int t = threadIdx.x, lane = t & 63, w = t >> 6;
  const int q = lane >> 4, e = lane & 15;
  const int nodebase = (blockIdx.x * 4 + w) * 16;

  // ---- stage ALL weights once: 48 KB Wn1 hi + 16 KB Wn2, 16 uint4 per thread ----
  {
    const uint4* s1 = (const uint4*)Wn1p;          // slabs 0-5 = first 48 KB
    const uint4* s2 = (const uint4*)Wn2p;          // slabs 0-3 = first 16 KB
    uint4* dst = (uint4*)wbuf;
#pragma unroll
    for (int i = 0; i < 12; ++i) dst[t + 256 * i] = s1[t + 256 * i];
#pragma unroll
    for (int i = 0; i < 4; ++i) dst[3072 + t + 256 * i] = s2[t + 256 * i];
  }
  __syncthreads();  // the ONLY barrier in this kernel

  f32x4 acc[8];
#pragma unroll
  for (int nt = 0; nt < 8; ++nt) acc[nt] = zero4();

  // ---- Layer 1: 6 slab sweeps (sr 0..5), hi+lo per bfv read ----
#pragma unroll
  for (int sr = 0; sr < 6; ++sr) {
    const int col = sr * 32 + q * 8;  // [0,192)
    const int node = nodebase + e;
    const float* p = (col < 64) ? (x + (size_t)node * 64 + col)
                                : (pooled + (size_t)node * 128 + (col - 64));
    bf16x8 afh, afl;
    make_frag2(p, &afh, &afl);
#pragma unroll
    for (int nt = 0; nt < 8; ++nt) {
      const bf16x8 bfv = *(const bf16x8*)(wbuf + sr * 4096 + (nt * 64 + lane) * 8);
      acc[nt] = __builtin_amdgcn_mfma_f32_16x16x32_bf16(afh, bfv, acc[nt], 0, 0, 0);
      acc[nt] = __builtin_amdgcn_mfma_f32_16x16x32_bf16(afl, bfv, acc[nt], 0, 0, 0);
    }
  }

  // ---- Epilogue-1 + Layer 2 interleaved in two 64-feat halves (kedge pattern) ----
  f32x4 acc2[4];
#pragma unroll
  for (int nt = 0; nt < 4; ++nt) acc2[nt] = zero4();

#pragma unroll
  for (int hh = 0; hh < 2; ++hh) {
    // epilogue-1 half: bias+relu -> bf16 hi -> wave-private A-frag buffer
#pragma unroll
    for (int nt4 = 0; nt4 < 4; ++nt4) {
      const int nt = hh * 4 + nt4;
      const int cc = nt * 16 + e;
      const float bv = bn1[cc];
      const int bse = (((cc >> 5) & 1) * 64 + q * 4 + 16 * ((cc >> 3) & 3)) * 8 + (cc & 7);
#pragma unroll
      for (int r = 0; r < 4; ++r)
        hfrag[w][bse + r * 8] = f2b(fmaxf(acc[nt][r] + bv, 0.f));
    }
    // L2 half: Wn2 slabs f = hh*2, hh*2+1
#pragma unroll
    for (int sl = 0; sl < 2; ++sl) {
      const int f = hh * 2 + sl;
      const bf16x8 a2 = *(const bf16x8*)(&hfrag[w][(sl * 64 + lane) * 8]);
      const bf16_t* wb2 = wbuf + 24576 + f * 2048;
#pragma unroll
      for (int nt = 0; nt < 4; ++nt) {
        const bf16x8 bfv = *(const bf16x8*)(wb2 + (nt * 64 + lane) * 8);
        acc2[nt] = __builtin_amdgcn_mfma_f32_16x16x32_bf16(a2, bfv, acc2[nt], 0, 0, 0);
      }
    }
  }

  // ---- Final: + bn2, * mask, store ----
  int mm[4];
#pragma unroll
  for (int r = 0; r < 4; ++r) mm[r] = mask[nodebase + q * 4 + r];
#pragma unroll
  for (int nt = 0; nt < 4; ++nt) {
    const float bv = bn2[nt * 16 + e];
#pragma unroll
    for (int r = 0; r < 4; ++r) {
      const int node = nodebase + q * 4 + r;
      out[(size_t)node * 64 + nt * 16 + e] = (acc2[nt][r] + bv) * (float)mm[r];
    }
  }
}

// ---------------- Launch ----------------
extern "C" void kernel_launch(void* const* d_in, const int* in_sizes, int n_in,
                              void* d_out, int out_size, void* d_ws, size_t ws_size,
                              hipStream_t stream) {
  const float* nodes = (const float*)d_in[0];
  const int*   mask  = (const int*)d_in[1];
  const float* We1   = (const float*)d_in[2];
  const float* be1   = (const float*)d_in[3];
  const float* We2   = (const float*)d_in[4];
  const float* be2   = (const float*)d_in[5];
  const float* Wn1   = (const float*)d_in[6];
  const float* bn1   = (const float*)d_in[7];
  const float* Wn2   = (const float*)d_in[8];
  const float* bn2   = (const float*)d_in[9];
  float* out = (float*)d_out;

  char* p = (char*)d_ws;
  auto alloc = [&](size_t bytes) -> char* {
    char* r = p;
    p += (bytes + 255) & ~(size_t)255;
    return r;
  };
  float*  x      = (float*)alloc((size_t)32768 * 64 * 4);
  bf16_t* xhi    = (bf16_t*)alloc((size_t)32768 * 64 * 2);
  bf16_t* xlo    = (bf16_t*)alloc((size_t)32768 * 64 * 2);
  float*  sq     = (float*)alloc((size_t)32768 * 4);
  int*    vlist  = (int*)alloc((size_t)32768 * 4);
  int*    vcnt   = (int*)alloc((size_t)64 * 4);
  int*    idxg   = (int*)alloc((size_t)32768 * 16 * 4);
  float*  pooled = (float*)alloc((size_t)32768 * 128 * 4);
  bf16_t* W1p    = (bf16_t*)alloc((size_t)8 * 8 * 64 * 8 * 2);
  bf16_t* W2p    = (bf16_t*)alloc((size_t)8 * 8 * 64 * 8 * 2);
  bf16_t* Wn1p   = (bf16_t*)alloc((size_t)12 * 8 * 64 * 8 * 2);
  bf16_t* Wn2p   = (bf16_t*)alloc((size_t)8 * 4 * 64 * 8 * 2);
  if ((size_t)(p - (char*)d_ws) > ws_size) return;  // workspace too small -> loud failure

  kfuse<<<640, 256, 0, stream>>>(nodes, mask, We1, We2, Wn1, Wn2,
                                 x, xhi, xlo, sq, vlist, vcnt, W1p, W2p, Wn1p, Wn2p);
  kknn<<<2048, 256, 0, stream>>>(xhi, xlo, sq, vlist, vcnt, idxg);
  kedge<<<512, 256, 0, stream>>>(xhi, xlo, idxg, vlist, vcnt, W1p, W2p, be1, be2, pooled);
  knode<<<512, 256, 0, stream>>>(x, pooled, mask, Wn1p, Wn2p, bn1, bn2, out);
}

// Round 12
// 167.721 us; speedup vs baseline: 1.0514x; 1.0514x over previous
//
#include <hip/hip_runtime.h>

#define DI __device__ __forceinline__

typedef __bf16 bf16_t;
typedef __bf16 bf16x4 __attribute__((ext_vector_type(4)));
typedef __bf16 bf16x8 __attribute__((ext_vector_type(8)));
typedef float f32x4 __attribute__((ext_vector_type(4)));
typedef unsigned long long u64;

// Problem constants
// B=64, N=512, F=64, H=128, FO=64, K=16

DI bf16_t f2b(float f) {
  unsigned u = __float_as_uint(f);
  unsigned r = (u + 0x7fffu + ((u >> 16) & 1u)) >> 16;
  return __builtin_bit_cast(bf16_t, (unsigned short)r);
}
DI float b2f(bf16_t h) {
  return __uint_as_float(((unsigned)__builtin_bit_cast(unsigned short, h)) << 16);
}
DI f32x4 zero4() { f32x4 z = {0.f, 0.f, 0.f, 0.f}; return z; }

DI bf16x8 make_frag(const float* p, bool wantlo) {
  float4 v0 = *(const float4*)p;
  float4 v1 = *(const float4*)(p + 4);
  float vv[8] = {v0.x, v0.y, v0.z, v0.w, v1.x, v1.y, v1.z, v1.w};
  bf16x8 a;
#pragma unroll
  for (int j = 0; j < 8; ++j) {
    bf16_t hi = f2b(vv[j]);
    a[j] = wantlo ? f2b(vv[j] - b2f(hi)) : hi;
  }
  return a;
}
// Both planes from one load (dedup for knode L1).
DI void make_frag2(const float* p, bf16x8* hi, bf16x8* lo) {
  float4 v0 = *(const float4*)p;
  float4 v1 = *(const float4*)(p + 4);
  float vv[8] = {v0.x, v0.y, v0.z, v0.w, v1.x, v1.y, v1.z, v1.w};
#pragma unroll
  for (int j = 0; j < 8; ++j) {
    bf16_t h = f2b(vv[j]);
    (*hi)[j] = h;
    (*lo)[j] = f2b(vv[j] - b2f(h));
  }
}

DI u64 u64min(u64 a, u64 b) { return a < b ? a : b; }
// ctrl must be an ICE for __builtin_amdgcn_update_dpp -> template parameter.
template <int CTRL>
DI u64 dpp_u64(u64 v) {
  int lo = (int)(unsigned)(v & 0xffffffffull);
  int hi = (int)(unsigned)(v >> 32);
  int tlo = __builtin_amdgcn_update_dpp(0, lo, CTRL, 0xF, 0xF, true);
  int thi = __builtin_amdgcn_update_dpp(0, hi, CTRL, 0xF, 0xF, true);
  return (((u64)(unsigned)thi) << 32) | (unsigned)tlo;
}
template <int CTRL>
DI float dpp_f32(float v) {
  int t = __builtin_amdgcn_update_dpp(0, (int)__float_as_uint(v), CTRL, 0xF, 0xF, true);
  return __uint_as_float((unsigned)t);
}
// Min over each 16-lane row; result uniform within the row.
DI u64 rowmin_u64(u64 v) {
  v = u64min(v, dpp_u64<0xB1>(v));
  v = u64min(v, dpp_u64<0x4E>(v));
  v = u64min(v, dpp_u64<0x141>(v));
  v = u64min(v, dpp_u64<0x140>(v));
  return v;
}
// Sum over each 16-lane row (butterfly); result uniform within the row.
DI float rowsum_f32(float v) {
  v += dpp_f32<0xB1>(v);
  v += dpp_f32<0x4E>(v);
  v += dpp_f32<0x141>(v);
  v += dpp_f32<0x140>(v);
  return v;
}
// Bitonic sort, 16 elements, ascending. 80 CAS, all indices compile-time.
DI void bitonic16(u64* a) {
#pragma unroll
  for (int k = 2; k <= 16; k <<= 1)
#pragma unroll
    for (int j = k >> 1; j > 0; j >>= 1)
#pragma unroll
      for (int i = 0; i < 16; ++i) {
        const int l = i ^ j;
        if (l > i) {
          const bool up = ((i & k) == 0);
          const bool sw = up ? (a[i] > a[l]) : (a[i] < a[l]);
          const u64 t0 = a[i], t1 = a[l];
          a[i] = sw ? t1 : t0;
          a[l] = sw ? t0 : t1;
        }
      }
}
// Insert k into ascending sorted a[16], dropping the max. INF insert = no-op.
DI void sorted_insert16(u64* a, u64 k) {
  u64 na[16];
#pragma unroll
  for (int p = 0; p < 16; ++p) {
    const bool cur_gt = (a[p] > k);
    const bool prv_le = (p == 0) ? true : (a[p - 1] <= k);
    na[p] = !cur_gt ? a[p] : (prv_le ? k : a[p - 1]);
  }
#pragma unroll
  for (int p = 0; p < 16; ++p) a[p] = na[p];
}

// ---------------- Kernel F: fused prep — xplanes (512) + compact (64) + pack (64) --
__global__ void __launch_bounds__(256) kfuse(const float* __restrict__ nodes,
    const int* __restrict__ mask,
    const float* __restrict__ We1, const float* __restrict__ We2,
    const float* __restrict__ Wn1, const float* __restrict__ Wn2,
    float* __restrict__ x, bf16_t* __restrict__ xhi, bf16_t* __restrict__ xlo,
    float* __restrict__ sq, int* __restrict__ vlist, int* __restrict__ vcnt,
    bf16_t* __restrict__ W1p, bf16_t* __restrict__ W2p,
    bf16_t* __restrict__ Wn1p, bf16_t* __restrict__ Wn2p) {
  const int blk = blockIdx.x, t = threadIdx.x;
  __shared__ int cnts[8];
  __shared__ int basep[8];

  if (blk < 512) {
    // ---- xplanes: batch b, nodes n0..n0+63; 16 threads per row ----
    const int b = blk >> 3, n0 = (blk & 7) * 64;
#pragma unroll
    for (int i = 0; i < 4; ++i) {
      const int idx = t + 256 * i;
      const int gi = b * 512 + n0 + (idx >> 4);
      const int fo = (idx & 15) * 4;
      const float fm = (float)mask[gi];
      const size_t ro = (size_t)gi * 64;
      float4 v = *(const float4*)(nodes + ro + fo);
      v.x *= fm; v.y *= fm; v.z *= fm; v.w *= fm;
      *(float4*)(x + ro + fo) = v;
      float vv[4] = {v.x, v.y, v.z, v.w};
      bf16x4 hh, ll;
#pragma unroll
      for (int k = 0; k < 4; ++k) {
        bf16_t hi = f2b(vv[k]);
        hh[k] = hi;
        ll[k] = f2b(vv[k] - b2f(hi));
      }
      *(bf16x4*)(xhi + ro + fo) = hh;
      *(bf16x4*)(xlo + ro + fo) = ll;
      float s = v.x * v.x + v.y * v.y + v.z * v.z + v.w * v.w;
      s = rowsum_f32(s);  // sum over the row's 16 lanes (uniform in row)
      if ((t & 15) == 0) sq[gi] = s;
    }
  } else if (blk < 576) {
    // ---- compaction: one block per batch ----
    const int b = blk - 512, lane = t & 63, w = t >> 6;
    unsigned long long bal[2]; int flag[2];
#pragma unroll
    for (int h = 0; h < 2; ++h) {
      flag[h] = (mask[b * 512 + h * 256 + t] != 0);
      bal[h] = __ballot(flag[h]);
      if (lane == 0) cnts[h * 4 + w] = __popcll(bal[h]);
    }
    __syncthreads();
    if (t == 0) {
      int a = 0;
      for (int c = 0; c < 8; ++c) { basep[c] = a; a += cnts[c]; }
      vcnt[b] = a;
    }
    __syncthreads();
#pragma unroll
    for (int h = 0; h < 2; ++h) {
      if (flag[h]) {
        const unsigned long long lt = (lane == 0) ? 0ull : (~0ull >> (64 - lane));
        const int pos = basep[h * 4 + w] + __popcll(bal[h] & lt);
        vlist[b * 512 + pos] = h * 256 + t;
      }
    }
  } else {
    // ---- weight pack ----
    int p = (blk - 576) * 256 + t;  // 0..16383
    const float* W; bf16_t* dst; int K, Nn, local, mode;
    if (p < 4096)       { W = We1; dst = W1p;  K = 128; Nn = 128; mode = 0; local = p; }
    else if (p < 8192)  { W = We2; dst = W2p;  K = 128; Nn = 128; mode = 1; local = p - 4096; }
    else if (p < 14336) { W = Wn1; dst = Wn1p; K = 192; Nn = 128; mode = 0; local = p - 8192; }
    else                { W = Wn2; dst = Wn2p; K = 128; Nn = 64;  mode = 1; local = p - 14336; }
    int lane = local & 63;
    int nnt = (Nn >> 4);
    int chunk = local >> 6;
    int nt = chunk % nnt;
    int s = chunk / nnt;
    int n = nt * 16 + (lane & 15);
    int kbase = s * 32 + ((lane >> 4) * 8);
    bf16x8 v;
#pragma unroll
    for (int j = 0; j < 8; ++j) {
      int kp = kbase + j;
      int region = kp / K;
      int kk = kp - region * K;
      float w = W[kk * Nn + n];
      bf16_t hi = f2b(w);
      v[j] = (mode == 1 && region == 1) ? f2b(w - b2f(hi)) : hi;
    }
    *(bf16x8*)(dst + (size_t)local * 8) = v;
  }
}

// ---------------- Kernel B: distances + top-16 — MFMA Gram, 4-deep B pipeline -----
__global__ void __launch_bounds__(256) kknn(const bf16_t* __restrict__ xhi,
    const bf16_t* __restrict__ xlo,
    const float* __restrict__ sq, const int* __restrict__ vlist,
    const int* __restrict__ vcnt, int* __restrict__ idxg) {
  const int b = blockIdx.x & 63, tile = blockIdx.x >> 6;
  const int nv = vcnt[b];
  if (tile * 16 >= nv) return;  // block-uniform, before any barrier
  const int t = threadIdx.x, lane = t & 63, w = t >> 6;
  const int i = lane >> 4, d = lane & 15;   // i: k-group / C-row group; d: C-col
  __shared__ float sqs[512];
  __shared__ int vls[512];
  __shared__ __align__(16) float S[16 * 520];   // 33.3 KB Gram tile (row stride 520)
  for (int k = t; k < 512; k += 256) { sqs[k] = sq[b * 512 + k]; vls[k] = vlist[b * 512 + k]; }
  __syncthreads();

  const size_t xb = (size_t)b * 512 * 64;

  // ---- A fragments: 16 receiver rows of this tile (A row m = d = lane&15) ----
  const int aslot = tile * 16 + d;
  const int arow = vls[aslot < nv ? aslot : 0];
  bf16x8 ah[2], al[2];
#pragma unroll
  for (int kh = 0; kh < 2; ++kh) {
    ah[kh] = *(const bf16x8*)(xhi + xb + (size_t)arow * 64 + kh * 32 + i * 8);
    al[kh] = *(const bf16x8*)(xlo + xb + (size_t)arow * 64 + kh * 32 + i * 8);
  }

  // receiver identity for selection (thread handles recv w*4+i)
  const int rslot = tile * 16 + w * 4 + i;
  const bool vrow = (rslot < nv);
  const int nrow = vls[rslot < nv ? rslot : 0];
  const float sqn = sqs[nrow];

  // ---- candidate row ids for this wave's tiles (ct = w + 4*jj) ----
  int crs[8];
#pragma unroll
  for (int jj = 0; jj < 8; ++jj) {
    const int c = (w + 4 * jj) * 16 + d;
    crs[jj] = vls[c < nv ? c : 0];
  }

  // ---- Gram tiles: 4-deep rolling B-frag pipeline, C -> LDS ----
  bf16x8 pbh[4][2], pbl[4][2];
#pragma unroll
  for (int jj = 0; jj < 4; ++jj) {
    if ((w + 4 * jj) * 16 < nv) {  // wave-uniform
#pragma unroll
      for (int kh = 0; kh < 2; ++kh) {
        pbh[jj][kh] = *(const bf16x8*)(xhi + xb + (size_t)crs[jj] * 64 + kh * 32 + i * 8);
        pbl[jj][kh] = *(const bf16x8*)(xlo + xb + (size_t)crs[jj] * 64 + kh * 32 + i * 8);
      }
    }
  }
#pragma unroll
  for (int jj = 0; jj < 8; ++jj) {
    const int ct = w + 4 * jj;
    if (ct * 16 < nv) {  // wave-uniform
      const int sl = jj & 3;  // compile-time (unrolled)
      // copy out, then refill the slot with tile jj+4 (loads issue before MFMAs)
      bf16x8 bh[2] = {pbh[sl][0], pbh[sl][1]};
      bf16x8 bl[2] = {pbl[sl][0], pbl[sl][1]};
      if (jj < 4 && (w + 4 * (jj + 4)) * 16 < nv) {
#pragma unroll
        for (int kh = 0; kh < 2; ++kh) {
          pbh[sl][kh] = *(const bf16x8*)(xhi + xb + (size_t)crs[jj + 4] * 64 + kh * 32 + i * 8);
          pbl[sl][kh] = *(const bf16x8*)(xlo + xb + (size_t)crs[jj + 4] * 64 + kh * 32 + i * 8);
        }
      }
      f32x4 acc = zero4();
#pragma unroll
      for (int kh = 0; kh < 2; ++kh) {
        acc = __builtin_amdgcn_mfma_f32_16x16x32_bf16(ah[kh], bh[kh], acc, 0, 0, 0);
        acc = __builtin_amdgcn_mfma_f32_16x16x32_bf16(ah[kh], bl[kh], acc, 0, 0, 0);
        acc = __builtin_amdgcn_mfma_f32_16x16x32_bf16(al[kh], bh[kh], acc, 0, 0, 0);
        acc = __builtin_amdgcn_mfma_f32_16x16x32_bf16(al[kh], bl[kh], acc, 0, 0, 0);
      }
      // D(m=recv=i*4+r, n=cand=d): S[recv][cand]
#pragma unroll
      for (int r = 0; r < 4; ++r) S[(i * 4 + r) * 520 + ct * 16 + d] = acc[r];
    }
  }
  __syncthreads();

  // ---- key build: first 16 j-groups -> s1; sort; overflow groups insert ----
  const u64 INF64 = ~0ull;
  u64 s1[16];
#pragma unroll
  for (int j = 0; j < 16; ++j) s1[j] = INF64;
#pragma unroll
  for (int j = 0; j < 16; ++j) {
    if (j * 16 < nv) {  // uniform
      const int c = j * 16 + d;
      const int m = vls[c < nv ? c : 0];
      const float dot = S[(w * 4 + i) * 520 + j * 16 + d];
      const float dd = fabsf(sqn + sqs[m] - 2.f * dot);
      const u64 key = (((u64)__float_as_uint(dd)) << 32) | (unsigned)m;
      const bool ok = (c < nv) && (m != nrow);
      s1[j] = ok ? key : INF64;
    }
  }
  bitonic16(s1);
  // overflow: slots 256.. (wave-uniform trip count, ~0-3 iterations typical)
  for (int j = 16; j * 16 < nv; ++j) {
    const int c = j * 16 + d;
    const int m = vls[c < nv ? c : 0];
    const float dot = S[(w * 4 + i) * 520 + j * 16 + d];
    const float dd = fabsf(sqn + sqs[m] - 2.f * dot);
    const u64 key = (((u64)__float_as_uint(dd)) << 32) | (unsigned)m;
    const bool ok = (c < nv) && (m != nrow);
    sorted_insert16(s1, ok ? key : INF64);
  }

  // ---- extraction: 16 rounds, single array ----
  int res = nrow;
#pragma unroll
  for (int ts = 0; ts < 16; ++ts) {
    const u64 wmin = rowmin_u64(s1[0]);
    if (d == ts) res = (wmin == INF64) ? nrow : (int)(unsigned)(wmin & 0xffffffffull);
    const bool w1 = (wmin != INF64) && (s1[0] == wmin);
#pragma unroll
    for (int k = 0; k < 15; ++k) s1[k] = w1 ? s1[k + 1] : s1[k];
    s1[15] = w1 ? INF64 : s1[15];
  }
  // SLOT-indexed store
  if (vrow) idxg[((size_t)b * 512 + rslot) * 16 + d] = res;
}

// ---------------- Kernel C: edge MLP — 8-wave block, ONE slot per wave ------------
// r11 regression root-cause: VGPR squeeze (pair-per-wave live set ~190 at cap 128)
// -> scratch spill (WRITE 33MB), plus W2-from-global on critical path. This round:
// r7's 8-wave idea done right. 512-thread blocks share the SAME 80 KB LDS
// (W1 32 + W2 32 + hfrag 8x2 KB) -> 2 blocks/CU = 16 waves/CU = 4 waves/SIMD
// (2x TLP vs r8). Each wave owns ONE slot per iteration: acc 32 + acc2 32 + af 32
// VGPR ~ 120 live, fits <=128 without forcing (__launch_bounds__(512,2) caps at
// 256 -> NO forced spill; r7's mistake was (512,4)->64). Per-slot math order
// unchanged -> FP bit-identical. W2 back in LDS.
__global__ void __launch_bounds__(512, 2) kedge(const bf16_t* __restrict__ xhi,
    const bf16_t* __restrict__ xlo, const int* __restrict__ idxg,
    const int* __restrict__ vlist, const int* __restrict__ vcnt,
    const bf16_t* __restrict__ W1p, const bf16_t* __restrict__ W2p,
    const float* __restrict__ be1, const float* __restrict__ be2,
    float* __restrict__ pooled) {
  __shared__ __align__(16) bf16_t wbuf[32768];    // 64 KB: W1 slabs0-3 | W2 slabs0-3
  __shared__ __align__(16) bf16_t hfrag[8][1024]; // 16 KB (half-H per wave)
  const int t = threadIdx.x, lane = t & 63, w = t >> 6;  // w in [0,8)
  const int q = lane >> 4, e = lane & 15;
  const int bb = blockIdx.x & 63;              // same-XCD batch grouping
  const int s0 = (blockIdx.x >> 6) * 8 + w;    // slot base 0..63, stride 64

  // ---- stage ALL weights once: 64 KB, 8 uint4 per thread (512 threads) ----
  {
    const uint4* s1 = (const uint4*)W1p;
    const uint4* s2 = (const uint4*)W2p;
    uint4* dst = (uint4*)wbuf;
#pragma unroll
    for (int i = 0; i < 4; ++i) dst[t + 512 * i] = s1[t + 512 * i];
#pragma unroll
    for (int i = 0; i < 4; ++i) dst[2048 + t + 512 * i] = s2[t + 512 * i];
  }
  __syncthreads();  // the ONLY barrier in this kernel

  const int nv = vcnt[bb];
  if (s0 >= nv) return;

  // slot loader: vlist value (wave-uniform) + 16 neighbor ids (slot-indexed idxg)
  int vl = vlist[bb * 512 + s0];
  int sv = idxg[((size_t)(bb * 512 + s0) << 4) + e];

  for (int base = s0; base < nv; base += 64) {
    const int gid = bb * 512 + vl;
    const size_t rb = (size_t)gid << 6;
    const size_t nb = (size_t)(bb * 512 + sv) << 6;

    // ---- issue all 8 A-fragment loads for this slot ----
    // af[k] k<4: receiver (ph0), k>=4: neighbors (ph1); (k&1)=inner, (k>>1)&1=lo
    bf16x8 af[8];
#pragma unroll
    for (int k = 0; k < 4; ++k) {
      const int off = (k & 1) * 32 + q * 8;
      const bf16_t* pl = (k >> 1) ? xlo : xhi;
      af[k]     = *(const bf16x8*)(pl + rb + off);
      af[4 + k] = *(const bf16x8*)(pl + nb + off);
    }

    // ---- prefetch next slot's indices (1-deep) ----
    int nvl = vl, nsv = sv;
    {
      const int nbs = base + 64;
      if (nbs < nv) {
        nvl = vlist[bb * 512 + nbs];
        nsv = idxg[((size_t)(bb * 512 + nbs) << 4) + e];
      }
    }

    // ---- Layer 1: slab-dedup — one bfv read feeds hi+lo ----
    f32x4 acc[8];
#pragma unroll
    for (int nt = 0; nt < 8; ++nt) acc[nt] = zero4();

#pragma unroll
    for (int ph = 0; ph < 2; ++ph)
#pragma unroll
      for (int inner = 0; inner < 2; ++inner) {
        const bf16_t* wb = wbuf + (ph * 2 + inner) * 4096;
        const bf16x8 h = af[ph * 4 + inner];
        const bf16x8 l = af[ph * 4 + 2 + inner];
#pragma unroll
        for (int nt = 0; nt < 8; ++nt) {
          const bf16x8 bfv = *(const bf16x8*)(wb + (nt * 64 + lane) * 8);
          acc[nt] = __builtin_amdgcn_mfma_f32_16x16x32_bf16(h, bfv, acc[nt], 0, 0, 0);
          acc[nt] = __builtin_amdgcn_mfma_f32_16x16x32_bf16(l, bfv, acc[nt], 0, 0, 0);
        }
      }

    // ---- L2 in two halves interleaved with epilogue-1 (same FP order) ----
    f32x4 acc2[8];
#pragma unroll
    for (int nt = 0; nt < 8; ++nt) acc2[nt] = zero4();

#pragma unroll
    for (int hh = 0; hh < 2; ++hh) {
      // epilogue-1 half: bias+relu -> bf16 hi -> wave-private A-frag buffer
#pragma unroll
      for (int nt4 = 0; nt4 < 4; ++nt4) {
        const int nt = hh * 4 + nt4;
        const int cc = nt * 16 + e;
        const float bv = be1[cc];
        const int bse = (((cc >> 5) & 1) * 64 + q * 4 + 16 * ((cc >> 3) & 3)) * 8 + (cc & 7);
#pragma unroll
        for (int r = 0; r < 4; ++r)
          hfrag[w][bse + r * 8] = f2b(fmaxf(acc[nt][r] + bv, 0.f));
      }
      // L2 half: W2 hi slabs f = hh*2, hh*2+1 (from LDS)
#pragma unroll
      for (int sl = 0; sl < 2; ++sl) {
        const int f = hh * 2 + sl;
        const bf16x8 a2 = *(const bf16x8*)(&hfrag[w][(sl * 64 + lane) * 8]);
        const bf16_t* wb2 = wbuf + 16384 + f * 4096;
#pragma unroll
        for (int nt = 0; nt < 8; ++nt) {
          const bf16x8 bfv = *(const bf16x8*)(wb2 + (nt * 64 + lane) * 8);
          acc2[nt] = __builtin_amdgcn_mfma_f32_16x16x32_bf16(a2, bfv, acc2[nt], 0, 0, 0);
        }
      }
    }

    // ---- Epilogue 2: bias+relu, mean over 16 edges (cnt==16 exactly) ----
#pragma unroll
    for (int nt = 0; nt < 8; ++nt) {
      const float bv = be2[nt * 16 + e];
      float part = 0.f;
#pragma unroll
      for (int r = 0; r < 4; ++r) part += fmaxf(acc2[nt][r] + bv, 0.f);
      part += __shfl_xor(part, 16, 64);
      part += __shfl_xor(part, 32, 64);
      if (lane < 16) pooled[(size_t)gid * 128 + nt * 16 + lane] = part * 0.0625f;
    }

    vl = nvl; sv = nsv;
  }
}

// ---------------- Kernel D: node MLP — persistent-weight + slab-dedup L1 ----------
__global__ void __launch_bounds__(256, 2) knode(const float* __restrict__ x,
    const float* __restrict__ pooled, const int* __restrict__ mask,
    const bf16_t* __restrict__ Wn1p, const bf16_t* __restrict__ Wn2p,
    const float* __restrict__ bn1, const float* __restrict__ bn2,
    float* __restrict__ out) {
  __shared__ __align__(16) bf16_t wbuf[32768];     // 64 KB: Wn1 slabs0-5 | Wn2 slabs0-3
  __shared__ __align__(16) bf16_t hfrag[4][1024];  // 8 KB (half-H per wave)
  const int t = threadIdx.x, lane = t & 63, w = t >> 6;
  const int q = lane >> 4, e = lane & 15;
  const int nodebase = (blockIdx.x * 4 + w) * 16;

  // ---- stage ALL weights once: 48 KB Wn1 hi + 16 KB Wn2, 16 uint4 per thread ----
  {
    const uint4* s1 = (const uint4*)Wn1p;          // slabs 0-5 = first 48 KB
    const uint4* s2 = (const uint4*)Wn2p;          // slabs 0-3 = first 16 KB
    uint4* dst = (uint4*)wbuf;
#pragma unroll
    for (int i = 0; i < 12; ++i) dst[t + 256 * i] = s1[t + 256 * i];
#pragma unroll
    for (int i = 0; i < 4; ++i) dst[3072 + t + 256 * i] = s2[t + 256 * i];
  }
  __syncthreads();  // the ONLY barrier in this kernel

  f32x4 acc[8];
#pragma unroll
  for (int nt = 0; nt < 8; ++nt) acc[nt] = zero4();

  // ---- Layer 1: 6 slab sweeps (sr 0..5), hi+lo per bfv read ----
#pragma unroll
  for (int sr = 0; sr < 6; ++sr) {
    const int col = sr * 32 + q * 8;  // [0,192)
    const int node = nodebase + e;
    const float* p = (col < 64) ? (x + (size_t)node * 64 + col)
                                : (pooled + (size_t)node * 128 + (col - 64));
    bf16x8 afh, afl;
    make_frag2(p, &afh, &afl);
#pragma unroll
    for (int nt = 0; nt < 8; ++nt) {
      const bf16x8 bfv = *(const bf16x8*)(wbuf + sr * 4096 + (nt * 64 + lane) * 8);
      acc[nt] = __builtin_amdgcn_mfma_f32_16x16x32_bf16(afh, bfv, acc[nt], 0, 0, 0);
      acc[nt] = __builtin_amdgcn_mfma_f32_16x16x32_bf16(afl, bfv, acc[nt], 0, 0, 0);
    }
  }

  // ---- Epilogue-1 + Layer 2 interleaved in two 64-feat halves (kedge pattern) ----
  f32x4 acc2[4];
#pragma unroll
  for (int nt = 0; nt < 4; ++nt) acc2[nt] = zero4();

#pragma unroll
  for (int hh = 0; hh < 2; ++hh) {
    // epilogue-1 half: bias+relu -> bf16 hi -> wave-private A-frag buffer
#pragma unroll
    for (int nt4 = 0; nt4 < 4; ++nt4) {
      const int nt = hh * 4 + nt4;
      const int cc = nt * 16 + e;
      const float bv = bn1[cc];
      const int bse = (((cc >> 5) & 1) * 64 + q * 4 + 16 * ((cc >> 3) & 3)) * 8 + (cc & 7);
#pragma unroll
      for (int r = 0; r < 4; ++r)
        hfrag[w][bse + r * 8] = f2b(fmaxf(acc[nt][r] + bv, 0.f));
    }
    // L2 half: Wn2 slabs f = hh*2, hh*2+1
#pragma unroll
    for (int sl = 0; sl < 2; ++sl) {
      const int f = hh * 2 + sl;
      const bf16x8 a2 = *(const bf16x8*)(&hfrag[w][(sl * 64 + lane) * 8]);
      const bf16_t* wb2 = wbuf + 24576 + f * 2048;
#pragma unroll
      for (int nt = 0; nt < 4; ++nt) {
        const bf16x8 bfv = *(const bf16x8*)(wb2 + (nt * 64 + lane) * 8);
        acc2[nt] = __builtin_amdgcn_mfma_f32_16x16x32_bf16(a2, bfv, acc2[nt], 0, 0, 0);
      }
    }
  }

  // ---- Final: + bn2, * mask, store ----
  int mm[4];
#pragma unroll
  for (int r = 0; r < 4; ++r) mm[r] = mask[nodebase + q * 4 + r];
#pragma unroll
  for (int nt = 0; nt < 4; ++nt) {
    const float bv = bn2[nt * 16 + e];
#pragma unroll
    for (int r = 0; r < 4; ++r) {
      const int node = nodebase + q * 4 + r;
      out[(size_t)node * 64 + nt * 16 + e] = (acc2[nt][r] + bv) * (float)mm[r];
    }
  }
}

// ---------------- Launch ----------------
extern "C" void kernel_launch(void* const* d_in, const int* in_sizes, int n_in,
                              void* d_out, int out_size, void* d_ws, size_t ws_size,
                              hipStream_t stream) {
  const float* nodes = (const float*)d_in[0];
  const int*   mask  = (const int*)d_in[1];
  const float* We1   = (const float*)d_in[2];
  const float* be1   = (const float*)d_in[3];
  const float* We2   = (const float*)d_in[4];
  const float* be2   = (const float*)d_in[5];
  const float* Wn1   = (const float*)d_in[6];
  const float* bn1   = (const float*)d_in[7];
  const float* Wn2   = (const float*)d_in[8];
  const float* bn2   = (const float*)d_in[9];
  float* out = (float*)d_out;

  char* p = (char*)d_ws;
  auto alloc = [&](size_t bytes) -> char* {
    char* r = p;
    p += (bytes + 255) & ~(size_t)255;
    return r;
  };
  float*  x      = (float*)alloc((size_t)32768 * 64 * 4);
  bf16_t* xhi    = (bf16_t*)alloc((size_t)32768 * 64 * 2);
  bf16_t* xlo    = (bf16_t*)alloc((size_t)32768 * 64 * 2);
  float*  sq     = (float*)alloc((size_t)32768 * 4);
  int*    vlist  = (int*)alloc((size_t)32768 * 4);
  int*    vcnt   = (int*)alloc((size_t)64 * 4);
  int*    idxg   = (int*)alloc((size_t)32768 * 16 * 4);
  float*  pooled = (float*)alloc((size_t)32768 * 128 * 4);
  bf16_t* W1p    = (bf16_t*)alloc((size_t)8 * 8 * 64 * 8 * 2);
  bf16_t* W2p    = (bf16_t*)alloc((size_t)8 * 8 * 64 * 8 * 2);
  bf16_t* Wn1p   = (bf16_t*)alloc((size_t)12 * 8 * 64 * 8 * 2);
  bf16_t* Wn2p   = (bf16_t*)alloc((size_t)8 * 4 * 64 * 8 * 2);
  if ((size_t)(p - (char*)d_ws) > ws_size) return;  // workspace too small -> loud failure

  kfuse<<<640, 256, 0, stream>>>(nodes, mask, We1, We2, Wn1, Wn2,
                                 x, xhi, xlo, sq, vlist, vcnt, W1p, W2p, Wn1p, Wn2p);
  kknn<<<2048, 256, 0, stream>>>(xhi, xlo, sq, vlist, vcnt, idxg);
  kedge<<<512, 512, 0, stream>>>(xhi, xlo, idxg, vlist, vcnt, W1p, W2p, be1, be2, pooled);
  knode<<<512, 256, 0, stream>>>(x, pooled, mask, Wn1p, Wn2p, bn1, bn2, out);
}

// Round 13
// 154.302 us; speedup vs baseline: 1.1428x; 1.0870x over previous
//
#include <hip/hip_runtime.h>

#define DI __device__ __forceinline__

typedef __bf16 bf16_t;
typedef __bf16 bf16x4 __attribute__((ext_vector_type(4)));
typedef __bf16 bf16x8 __attribute__((ext_vector_type(8)));
typedef float f32x4 __attribute__((ext_vector_type(4)));
typedef unsigned long long u64;

// Problem constants
// B=64, N=512, F=64, H=128, FO=64, K=16

DI bf16_t f2b(float f) {
  unsigned u = __float_as_uint(f);
  unsigned r = (u + 0x7fffu + ((u >> 16) & 1u)) >> 16;
  return __builtin_bit_cast(bf16_t, (unsigned short)r);
}
DI float b2f(bf16_t h) {
  return __uint_as_float(((unsigned)__builtin_bit_cast(unsigned short, h)) << 16);
}
DI f32x4 zero4() { f32x4 z = {0.f, 0.f, 0.f, 0.f}; return z; }

// Both planes from one f32 load (knode L1, pooled region).
DI void make_frag2(const float* p, bf16x8* hi, bf16x8* lo) {
  float4 v0 = *(const float4*)p;
  float4 v1 = *(const float4*)(p + 4);
  float vv[8] = {v0.x, v0.y, v0.z, v0.w, v1.x, v1.y, v1.z, v1.w};
#pragma unroll
  for (int j = 0; j < 8; ++j) {
    bf16_t h = f2b(vv[j]);
    (*hi)[j] = h;
    (*lo)[j] = f2b(vv[j] - b2f(h));
  }
}

DI u64 u64min(u64 a, u64 b) { return a < b ? a : b; }
// ctrl must be an ICE for __builtin_amdgcn_update_dpp -> template parameter.
template <int CTRL>
DI u64 dpp_u64(u64 v) {
  int lo = (int)(unsigned)(v & 0xffffffffull);
  int hi = (int)(unsigned)(v >> 32);
  int tlo = __builtin_amdgcn_update_dpp(0, lo, CTRL, 0xF, 0xF, true);
  int thi = __builtin_amdgcn_update_dpp(0, hi, CTRL, 0xF, 0xF, true);
  return (((u64)(unsigned)thi) << 32) | (unsigned)tlo;
}
template <int CTRL>
DI float dpp_f32(float v) {
  int t = __builtin_amdgcn_update_dpp(0, (int)__float_as_uint(v), CTRL, 0xF, 0xF, true);
  return __uint_as_float((unsigned)t);
}
// Min over each 16-lane row; result uniform within the row.
DI u64 rowmin_u64(u64 v) {
  v = u64min(v, dpp_u64<0xB1>(v));
  v = u64min(v, dpp_u64<0x4E>(v));
  v = u64min(v, dpp_u64<0x141>(v));
  v = u64min(v, dpp_u64<0x140>(v));
  return v;
}
// Sum over each 16-lane row (butterfly); result uniform within the row.
DI float rowsum_f32(float v) {
  v += dpp_f32<0xB1>(v);
  v += dpp_f32<0x4E>(v);
  v += dpp_f32<0x141>(v);
  v += dpp_f32<0x140>(v);
  return v;
}
// Bitonic sort, 16 elements, ascending. 80 CAS, all indices compile-time.
DI void bitonic16(u64* a) {
#pragma unroll
  for (int k = 2; k <= 16; k <<= 1)
#pragma unroll
    for (int j = k >> 1; j > 0; j >>= 1)
#pragma unroll
      for (int i = 0; i < 16; ++i) {
        const int l = i ^ j;
        if (l > i) {
          const bool up = ((i & k) == 0);
          const bool sw = up ? (a[i] > a[l]) : (a[i] < a[l]);
          const u64 t0 = a[i], t1 = a[l];
          a[i] = sw ? t1 : t0;
          a[l] = sw ? t0 : t1;
        }
      }
}
// Insert k into ascending sorted a[16], dropping the max. INF insert = no-op.
DI void sorted_insert16(u64* a, u64 k) {
  u64 na[16];
#pragma unroll
  for (int p = 0; p < 16; ++p) {
    const bool cur_gt = (a[p] > k);
    const bool prv_le = (p == 0) ? true : (a[p - 1] <= k);
    na[p] = !cur_gt ? a[p] : (prv_le ? k : a[p - 1]);
  }
#pragma unroll
  for (int p = 0; p < 16; ++p) a[p] = na[p];
}

// ---------------- Kernel F: fused prep — xplanes (512) + compact (64) + pack (64) --
// vs r10: f32 x plane DROPPED (its only consumer, knode L1 cols<64, now reads
// xhi/xlo directly — bit-identical since make_frag2(x) == stored planes).
__global__ void __launch_bounds__(256) kfuse(const float* __restrict__ nodes,
    const int* __restrict__ mask,
    const float* __restrict__ We1, const float* __restrict__ We2,
    const float* __restrict__ Wn1, const float* __restrict__ Wn2,
    bf16_t* __restrict__ xhi, bf16_t* __restrict__ xlo,
    float* __restrict__ sq, int* __restrict__ vlist, int* __restrict__ vcnt,
    bf16_t* __restrict__ W1p, bf16_t* __restrict__ W2p,
    bf16_t* __restrict__ Wn1p, bf16_t* __restrict__ Wn2p) {
  const int blk = blockIdx.x, t = threadIdx.x;
  __shared__ int cnts[8];
  __shared__ int basep[8];

  if (blk < 512) {
    // ---- xplanes: batch b, nodes n0..n0+63; 16 threads per row ----
    const int b = blk >> 3, n0 = (blk & 7) * 64;
#pragma unroll
    for (int i = 0; i < 4; ++i) {
      const int idx = t + 256 * i;
      const int gi = b * 512 + n0 + (idx >> 4);
      const int fo = (idx & 15) * 4;
      const float fm = (float)mask[gi];
      const size_t ro = (size_t)gi * 64;
      float4 v = *(const float4*)(nodes + ro + fo);
      v.x *= fm; v.y *= fm; v.z *= fm; v.w *= fm;
      float vv[4] = {v.x, v.y, v.z, v.w};
      bf16x4 hh, ll;
#pragma unroll
      for (int k = 0; k < 4; ++k) {
        bf16_t hi = f2b(vv[k]);
        hh[k] = hi;
        ll[k] = f2b(vv[k] - b2f(hi));
      }
      *(bf16x4*)(xhi + ro + fo) = hh;
      *(bf16x4*)(xlo + ro + fo) = ll;
      float s = v.x * v.x + v.y * v.y + v.z * v.z + v.w * v.w;
      s = rowsum_f32(s);  // sum over the row's 16 lanes (uniform in row)
      if ((t & 15) == 0) sq[gi] = s;
    }
  } else if (blk < 576) {
    // ---- compaction: one block per batch ----
    const int b = blk - 512, lane = t & 63, w = t >> 6;
    unsigned long long bal[2]; int flag[2];
#pragma unroll
    for (int h = 0; h < 2; ++h) {
      flag[h] = (mask[b * 512 + h * 256 + t] != 0);
      bal[h] = __ballot(flag[h]);
      if (lane == 0) cnts[h * 4 + w] = __popcll(bal[h]);
    }
    __syncthreads();
    if (t == 0) {
      int a = 0;
      for (int c = 0; c < 8; ++c) { basep[c] = a; a += cnts[c]; }
      vcnt[b] = a;
    }
    __syncthreads();
#pragma unroll
    for (int h = 0; h < 2; ++h) {
      if (flag[h]) {
        const unsigned long long lt = (lane == 0) ? 0ull : (~0ull >> (64 - lane));
        const int pos = basep[h * 4 + w] + __popcll(bal[h] & lt);
        vlist[b * 512 + pos] = h * 256 + t;
      }
    }
  } else {
    // ---- weight pack ----
    int p = (blk - 576) * 256 + t;  // 0..16383
    const float* W; bf16_t* dst; int K, Nn, local, mode;
    if (p < 4096)       { W = We1; dst = W1p;  K = 128; Nn = 128; mode = 0; local = p; }
    else if (p < 8192)  { W = We2; dst = W2p;  K = 128; Nn = 128; mode = 1; local = p - 4096; }
    else if (p < 14336) { W = Wn1; dst = Wn1p; K = 192; Nn = 128; mode = 0; local = p - 8192; }
    else                { W = Wn2; dst = Wn2p; K = 128; Nn = 64;  mode = 1; local = p - 14336; }
    int lane = local & 63;
    int nnt = (Nn >> 4);
    int chunk = local >> 6;
    int nt = chunk % nnt;
    int s = chunk / nnt;
    int n = nt * 16 + (lane & 15);
    int kbase = s * 32 + ((lane >> 4) * 8);
    bf16x8 v;
#pragma unroll
    for (int j = 0; j < 8; ++j) {
      int kp = kbase + j;
      int region = kp / K;
      int kk = kp - region * K;
      float w = W[kk * Nn + n];
      bf16_t hi = f2b(w);
      v[j] = (mode == 1 && region == 1) ? f2b(w - b2f(hi)) : hi;
    }
    *(bf16x8*)(dst + (size_t)local * 8) = v;
  }
}

// ---------------- Kernel B: distances + top-16 — MFMA Gram, 4-deep B pipeline -----
__global__ void __launch_bounds__(256) kknn(const bf16_t* __restrict__ xhi,
    const bf16_t* __restrict__ xlo,
    const float* __restrict__ sq, const int* __restrict__ vlist,
    const int* __restrict__ vcnt, int* __restrict__ idxg) {
  const int b = blockIdx.x & 63, tile = blockIdx.x >> 6;
  const int nv = vcnt[b];
  if (tile * 16 >= nv) return;  // block-uniform, before any barrier
  const int t = threadIdx.x, lane = t & 63, w = t >> 6;
  const int i = lane >> 4, d = lane & 15;   // i: k-group / C-row group; d: C-col
  __shared__ float sqs[512];
  __shared__ int vls[512];
  __shared__ __align__(16) float S[16 * 520];   // 33.3 KB Gram tile (row stride 520)
  for (int k = t; k < 512; k += 256) { sqs[k] = sq[b * 512 + k]; vls[k] = vlist[b * 512 + k]; }
  __syncthreads();

  const size_t xb = (size_t)b * 512 * 64;

  // ---- A fragments: 16 receiver rows of this tile (A row m = d = lane&15) ----
  const int aslot = tile * 16 + d;
  const int arow = vls[aslot < nv ? aslot : 0];
  bf16x8 ah[2], al[2];
#pragma unroll
  for (int kh = 0; kh < 2; ++kh) {
    ah[kh] = *(const bf16x8*)(xhi + xb + (size_t)arow * 64 + kh * 32 + i * 8);
    al[kh] = *(const bf16x8*)(xlo + xb + (size_t)arow * 64 + kh * 32 + i * 8);
  }

  // receiver identity for selection (thread handles recv w*4+i)
  const int rslot = tile * 16 + w * 4 + i;
  const bool vrow = (rslot < nv);
  const int nrow = vls[rslot < nv ? rslot : 0];
  const float sqn = sqs[nrow];

  // ---- candidate row ids for this wave's tiles (ct = w + 4*jj) ----
  int crs[8];
#pragma unroll
  for (int jj = 0; jj < 8; ++jj) {
    const int c = (w + 4 * jj) * 16 + d;
    crs[jj] = vls[c < nv ? c : 0];
  }

  // ---- Gram tiles: 4-deep rolling B-frag pipeline, C -> LDS ----
  bf16x8 pbh[4][2], pbl[4][2];
#pragma unroll
  for (int jj = 0; jj < 4; ++jj) {
    if ((w + 4 * jj) * 16 < nv) {  // wave-uniform
#pragma unroll
      for (int kh = 0; kh < 2; ++kh) {
        pbh[jj][kh] = *(const bf16x8*)(xhi + xb + (size_t)crs[jj] * 64 + kh * 32 + i * 8);
        pbl[jj][kh] = *(const bf16x8*)(xlo + xb + (size_t)crs[jj] * 64 + kh * 32 + i * 8);
      }
    }
  }
#pragma unroll
  for (int jj = 0; jj < 8; ++jj) {
    const int ct = w + 4 * jj;
    if (ct * 16 < nv) {  // wave-uniform
      const int sl = jj & 3;  // compile-time (unrolled)
      // copy out, then refill the slot with tile jj+4 (loads issue before MFMAs)
      bf16x8 bh[2] = {pbh[sl][0], pbh[sl][1]};
      bf16x8 bl[2] = {pbl[sl][0], pbl[sl][1]};
      if (jj < 4 && (w + 4 * (jj + 4)) * 16 < nv) {
#pragma unroll
        for (int kh = 0; kh < 2; ++kh) {
          pbh[sl][kh] = *(const bf16x8*)(xhi + xb + (size_t)crs[jj + 4] * 64 + kh * 32 + i * 8);
          pbl[sl][kh] = *(const bf16x8*)(xlo + xb + (size_t)crs[jj + 4] * 64 + kh * 32 + i * 8);
        }
      }
      f32x4 acc = zero4();
#pragma unroll
      for (int kh = 0; kh < 2; ++kh) {
        acc = __builtin_amdgcn_mfma_f32_16x16x32_bf16(ah[kh], bh[kh], acc, 0, 0, 0);
        acc = __builtin_amdgcn_mfma_f32_16x16x32_bf16(ah[kh], bl[kh], acc, 0, 0, 0);
        acc = __builtin_amdgcn_mfma_f32_16x16x32_bf16(al[kh], bh[kh], acc, 0, 0, 0);
        acc = __builtin_amdgcn_mfma_f32_16x16x32_bf16(al[kh], bl[kh], acc, 0, 0, 0);
      }
      // D(m=recv=i*4+r, n=cand=d): S[recv][cand]
#pragma unroll
      for (int r = 0; r < 4; ++r) S[(i * 4 + r) * 520 + ct * 16 + d] = acc[r];
    }
  }
  __syncthreads();

  // ---- key build: first 16 j-groups -> s1; sort; overflow groups insert ----
  const u64 INF64 = ~0ull;
  u64 s1[16];
#pragma unroll
  for (int j = 0; j < 16; ++j) s1[j] = INF64;
#pragma unroll
  for (int j = 0; j < 16; ++j) {
    if (j * 16 < nv) {  // uniform
      const int c = j * 16 + d;
      const int m = vls[c < nv ? c : 0];
      const float dot = S[(w * 4 + i) * 520 + j * 16 + d];
      const float dd = fabsf(sqn + sqs[m] - 2.f * dot);
      const u64 key = (((u64)__float_as_uint(dd)) << 32) | (unsigned)m;
      const bool ok = (c < nv) && (m != nrow);
      s1[j] = ok ? key : INF64;
    }
  }
  bitonic16(s1);
  // overflow: slots 256.. (wave-uniform trip count, ~0-3 iterations typical)
  for (int j = 16; j * 16 < nv; ++j) {
    const int c = j * 16 + d;
    const int m = vls[c < nv ? c : 0];
    const float dot = S[(w * 4 + i) * 520 + j * 16 + d];
    const float dd = fabsf(sqn + sqs[m] - 2.f * dot);
    const u64 key = (((u64)__float_as_uint(dd)) << 32) | (unsigned)m;
    const bool ok = (c < nv) && (m != nrow);
    sorted_insert16(s1, ok ? key : INF64);
  }

  // ---- extraction: 16 rounds, single array ----
  int res = nrow;
#pragma unroll
  for (int ts = 0; ts < 16; ++ts) {
    const u64 wmin = rowmin_u64(s1[0]);
    if (d == ts) res = (wmin == INF64) ? nrow : (int)(unsigned)(wmin & 0xffffffffull);
    const bool w1 = (wmin != INF64) && (s1[0] == wmin);
#pragma unroll
    for (int k = 0; k < 15; ++k) s1[k] = w1 ? s1[k + 1] : s1[k];
    s1[15] = w1 ? INF64 : s1[15];
  }
  // SLOT-indexed store
  if (vrow) idxg[((size_t)b * 512 + rslot) * 16 + d] = res;
}

// ---------------- Kernel C: edge MLP — persistent-weight (r10 proven best) --------
// Structural plateau ~42us: LDS 80KB caps 2 blocks/CU AND live set ~116 VGPR; r9-r12
// showed every occupancy/scheduling lever either neutral or spills. Do not squeeze.
__global__ void __launch_bounds__(256, 2) kedge(const bf16_t* __restrict__ xhi,
    const bf16_t* __restrict__ xlo, const int* __restrict__ idxg,
    const int* __restrict__ vlist, const int* __restrict__ vcnt,
    const bf16_t* __restrict__ W1p, const bf16_t* __restrict__ W2p,
    const float* __restrict__ be1, const float* __restrict__ be2,
    float* __restrict__ pooled) {
  __shared__ __align__(16) bf16_t wbuf[32768];       // 64 KB: W1 slabs0-3 | W2 slabs0-3
  __shared__ __align__(16) bf16_t hfrag[4][2][1024]; // 16 KB (half-H per u per wave)
  const int t = threadIdx.x, lane = t & 63, w = t >> 6;
  const int q = lane >> 4, e = lane & 15;
  const int bb = blockIdx.x & 63;              // same-XCD batch grouping
  const int s0 = ((blockIdx.x >> 6) * 4 + w) * 2;  // even slot base 0..62

  // ---- stage ALL weights once: 64 KB, 16 uint4 per thread ----
  {
    const uint4* s1 = (const uint4*)W1p;
    const uint4* s2 = (const uint4*)W2p;
    uint4* dst = (uint4*)wbuf;
#pragma unroll
    for (int i = 0; i < 8; ++i) dst[t + 256 * i] = s1[t + 256 * i];
#pragma unroll
    for (int i = 0; i < 8; ++i) dst[2048 + t + 256 * i] = s2[t + 256 * i];
  }
  __syncthreads();  // the ONLY barrier in this kernel

  const int nv = vcnt[bb];
  if (s0 >= nv) return;

  // slot-pair loader: vlist value (wave-uniform) + 16 neighbor ids (slot-indexed idxg)
  int vl[2], sv[2];
#pragma unroll
  for (int u = 0; u < 2; ++u) {
    const int sl = (s0 + u) < nv ? (s0 + u) : 0;
    vl[u] = vlist[bb * 512 + sl];
    sv[u] = idxg[((size_t)(bb * 512 + sl) << 4) + e];
  }

  // ---- preload A-frags for the first slot-pair ----
  // af[u][k] k<4: receiver (ph0), k>=4: neighbors (ph1); (k&1)=inner, (k>>1)&1=lo
  bf16x8 af[2][8];
  {
    const size_t rb0 = (size_t)(bb * 512 + vl[0]) << 6;
    const size_t rb1 = (size_t)(bb * 512 + vl[1]) << 6;
    const size_t nb0 = (size_t)(bb * 512 + sv[0]) << 6;
    const size_t nb1 = (size_t)(bb * 512 + sv[1]) << 6;
#pragma unroll
    for (int k = 0; k < 4; ++k) {
      const int off = (k & 1) * 32 + q * 8;
      const bf16_t* pl = (k >> 1) ? xlo : xhi;
      af[0][k]     = *(const bf16x8*)(pl + rb0 + off);
      af[1][k]     = *(const bf16x8*)(pl + rb1 + off);
      af[0][4 + k] = *(const bf16x8*)(pl + nb0 + off);
      af[1][4 + k] = *(const bf16x8*)(pl + nb1 + off);
    }
  }

  for (int base = s0; base < nv; base += 64) {
    const bool act1 = (base + 1) < nv;
    const bool hasnext = (base + 64) < nv;
    const int gid0 = bb * 512 + vl[0];
    const int gid1 = bb * 512 + vl[1];

    // ---- prefetch next slot pair's vlist/idxg (issued before L1) ----
    int nvl[2] = {vl[0], vl[1]}, nsv[2] = {sv[0], sv[1]};
    if (hasnext) {
#pragma unroll
      for (int u = 0; u < 2; ++u) {
        const int sl = (base + 64 + u) < nv ? (base + 64 + u) : 0;
        nvl[u] = vlist[bb * 512 + sl];
        nsv[u] = idxg[((size_t)(bb * 512 + sl) << 4) + e];
      }
    }

    // ---- Layer 1: slab-dedup — one bfv read feeds hi+lo for both u ----
    f32x4 acc[2][8];
#pragma unroll
    for (int u = 0; u < 2; ++u)
#pragma unroll
      for (int nt = 0; nt < 8; ++nt) acc[u][nt] = zero4();

#pragma unroll
    for (int ph = 0; ph < 2; ++ph)
#pragma unroll
      for (int inner = 0; inner < 2; ++inner) {
        const bf16_t* wb = wbuf + (ph * 2 + inner) * 4096;
        const bf16x8 h0 = af[0][ph * 4 + inner];
        const bf16x8 h1 = af[1][ph * 4 + inner];
        const bf16x8 l0 = af[0][ph * 4 + 2 + inner];
        const bf16x8 l1 = af[1][ph * 4 + 2 + inner];
#pragma unroll
        for (int nt = 0; nt < 8; ++nt) {
          const bf16x8 bfv = *(const bf16x8*)(wb + (nt * 64 + lane) * 8);
          acc[0][nt] = __builtin_amdgcn_mfma_f32_16x16x32_bf16(h0, bfv, acc[0][nt], 0, 0, 0);
          acc[0][nt] = __builtin_amdgcn_mfma_f32_16x16x32_bf16(l0, bfv, acc[0][nt], 0, 0, 0);
          acc[1][nt] = __builtin_amdgcn_mfma_f32_16x16x32_bf16(h1, bfv, acc[1][nt], 0, 0, 0);
          acc[1][nt] = __builtin_amdgcn_mfma_f32_16x16x32_bf16(l1, bfv, acc[1][nt], 0, 0, 0);
        }
      }

    // ---- issue next slot-pair's A-frag gathers (hide under L2+epilogues) ----
    bf16x8 naf[2][8];
    if (hasnext) {
      const size_t rb0n = (size_t)(bb * 512 + nvl[0]) << 6;
      const size_t rb1n = (size_t)(bb * 512 + nvl[1]) << 6;
      const size_t nb0n = (size_t)(bb * 512 + nsv[0]) << 6;
      const size_t nb1n = (size_t)(bb * 512 + nsv[1]) << 6;
#pragma unroll
      for (int k = 0; k < 4; ++k) {
        const int off = (k & 1) * 32 + q * 8;
        const bf16_t* pl = (k >> 1) ? xlo : xhi;
        naf[0][k]     = *(const bf16x8*)(pl + rb0n + off);
        naf[1][k]     = *(const bf16x8*)(pl + rb1n + off);
        naf[0][4 + k] = *(const bf16x8*)(pl + nb0n + off);
        naf[1][4 + k] = *(const bf16x8*)(pl + nb1n + off);
      }
    }

    // ---- L2 in two halves interleaved with epilogue-1 (same FP order as before) ----
    f32x4 acc2[2][8];
#pragma unroll
    for (int u = 0; u < 2; ++u)
#pragma unroll
      for (int nt = 0; nt < 8; ++nt) acc2[u][nt] = zero4();

#pragma unroll
    for (int hh = 0; hh < 2; ++hh) {
      // epilogue-1 half: bias+relu -> bf16 hi -> wave-private A-frag buffer
#pragma unroll
      for (int u = 0; u < 2; ++u)
#pragma unroll
        for (int nt4 = 0; nt4 < 4; ++nt4) {
          const int nt = hh * 4 + nt4;
          const int cc = nt * 16 + e;
          const float bv = be1[cc];
          const int bse = (((cc >> 5) & 1) * 64 + q * 4 + 16 * ((cc >> 3) & 3)) * 8 + (cc & 7);
#pragma unroll
          for (int r = 0; r < 4; ++r)
            hfrag[w][u][bse + r * 8] = f2b(fmaxf(acc[u][nt][r] + bv, 0.f));
        }
      // L2 half: W2 hi slabs f = hh*2, hh*2+1
#pragma unroll
      for (int sl = 0; sl < 2; ++sl) {
        const int f = hh * 2 + sl;
        const bf16x8 a20 = *(const bf16x8*)(&hfrag[w][0][(sl * 64 + lane) * 8]);
        const bf16x8 a21 = *(const bf16x8*)(&hfrag[w][1][(sl * 64 + lane) * 8]);
        const bf16_t* wb2 = wbuf + 16384 + f * 4096;
#pragma unroll
        for (int nt = 0; nt < 8; ++nt) {
          const bf16x8 bfv = *(const bf16x8*)(wb2 + (nt * 64 + lane) * 8);
          acc2[0][nt] = __builtin_amdgcn_mfma_f32_16x16x32_bf16(a20, bfv, acc2[0][nt], 0, 0, 0);
          acc2[1][nt] = __builtin_amdgcn_mfma_f32_16x16x32_bf16(a21, bfv, acc2[1][nt], 0, 0, 0);
        }
      }
    }

    // ---- Epilogue 2: bias+relu, mean over 16 edges (cnt==16 exactly) ----
#pragma unroll
    for (int u = 0; u < 2; ++u) {
      if (u == 0 || act1) {
        const int gid = u ? gid1 : gid0;
#pragma unroll
        for (int nt = 0; nt < 8; ++nt) {
          const float bv = be2[nt * 16 + e];
          float part = 0.f;
#pragma unroll
          for (int r = 0; r < 4; ++r) part += fmaxf(acc2[u][nt][r] + bv, 0.f);
          part += __shfl_xor(part, 16, 64);
          part += __shfl_xor(part, 32, 64);
          if (lane < 16) pooled[(size_t)gid * 128 + nt * 16 + lane] = part * 0.0625f;
        }
      }
    }

    // ---- rotate double buffer ----
    if (hasnext) {
#pragma unroll
      for (int u = 0; u < 2; ++u)
#pragma unroll
        for (int k = 0; k < 8; ++k) af[u][k] = naf[u][k];
      vl[0] = nvl[0]; vl[1] = nvl[1];
      sv[0] = nsv[0]; sv[1] = nsv[1];
    }
  }
}

// ---------------- Kernel D: node MLP — persistent-weight, planes-direct L1 --------
// vs r10: L1 cols<64 (sr 0,1) load xhi/xlo DIRECTLY (bit-identical to make_frag2(x):
// the planes store exactly f2b(v) and f2b(v-b2f(f2b(v)))). Halves those loads' bytes
// and removes ~24 VALU/iter of conversion; the f32 x plane is now fully dead.
__global__ void __launch_bounds__(256, 2) knode(const bf16_t* __restrict__ xhi,
    const bf16_t* __restrict__ xlo,
    const float* __restrict__ pooled, const int* __restrict__ mask,
    const bf16_t* __restrict__ Wn1p, const bf16_t* __restrict__ Wn2p,
    const float* __restrict__ bn1, const float* __restrict__ bn2,
    float* __restrict__ out) {
  __shared__ __align__(16) bf16_t wbuf[32768];     // 64 KB: Wn1 slabs0-5 | Wn2 slabs0-3
  __shared__ __align__(16) bf16_t hfrag[4][1024];  // 8 KB (half-H per wave)
  const int t = threadIdx.x, lane = t & 63, w = t >> 6;
  const int q = lane >> 4, e = lane & 15;
  const int nodebase = (blockIdx.x * 4 + w) * 16;

  // ---- stage ALL weights once: 48 KB Wn1 hi + 16 KB Wn2, 16 uint4 per thread ----
  {
    const uint4* s1 = (const uint4*)Wn1p;          // slabs 0-5 = first 48 KB
    const uint4* s2 = (const uint4*)Wn2p;          // slabs 0-3 = first 16 KB
    uint4* dst = (uint4*)wbuf;
#pragma unroll
    for (int i = 0; i < 12; ++i) dst[t + 256 * i] = s1[t + 256 * i];
#pragma unroll
    for (int i = 0; i < 4; ++i) dst[3072 + t + 256 * i] = s2[t + 256 * i];
  }
  __syncthreads();  // the ONLY barrier in this kernel

  f32x4 acc[8];
#pragma unroll
  for (int nt = 0; nt < 8; ++nt) acc[nt] = zero4();

  // ---- Layer 1: 6 slab sweeps (sr 0..5), hi+lo per bfv read ----
#pragma unroll
  for (int sr = 0; sr < 6; ++sr) {
    const int col = sr * 32 + q * 8;  // [0,192)
    const int node = nodebase + e;
    bf16x8 afh, afl;
    if (sr < 2) {  // x region: planes direct (bit-identical to make_frag2 on x)
      afh = *(const bf16x8*)(xhi + (size_t)node * 64 + col);
      afl = *(const bf16x8*)(xlo + (size_t)node * 64 + col);
    } else {       // pooled region
      make_frag2(pooled + (size_t)node * 128 + (col - 64), &afh, &afl);
    }
#pragma unroll
    for (int nt = 0; nt < 8; ++nt) {
      const bf16x8 bfv = *(const bf16x8*)(wbuf + sr * 4096 + (nt * 64 + lane) * 8);
      acc[nt] = __builtin_amdgcn_mfma_f32_16x16x32_bf16(afh, bfv, acc[nt], 0, 0, 0);
      acc[nt] = __builtin_amdgcn_mfma_f32_16x16x32_bf16(afl, bfv, acc[nt], 0, 0, 0);
    }
  }

  // ---- Epilogue-1 + Layer 2 interleaved in two 64-feat halves (kedge pattern) ----
  f32x4 acc2[4];
#pragma unroll
  for (int nt = 0; nt < 4; ++nt) acc2[nt] = zero4();

#pragma unroll
  for (int hh = 0; hh < 2; ++hh) {
    // epilogue-1 half: bias+relu -> bf16 hi -> wave-private A-frag buffer
#pragma unroll
    for (int nt4 = 0; nt4 < 4; ++nt4) {
      const int nt = hh * 4 + nt4;
      const int cc = nt * 16 + e;
      const float bv = bn1[cc];
      const int bse = (((cc >> 5) & 1) * 64 + q * 4 + 16 * ((cc >> 3) & 3)) * 8 + (cc & 7);
#pragma unroll
      for (int r = 0; r < 4; ++r)
        hfrag[w][bse + r * 8] = f2b(fmaxf(acc[nt][r] + bv, 0.f));
    }
    // L2 half: Wn2 slabs f = hh*2, hh*2+1
#pragma unroll
    for (int sl = 0; sl < 2; ++sl) {
      const int f = hh * 2 + sl;
      const bf16x8 a2 = *(const bf16x8*)(&hfrag[w][(sl * 64 + lane) * 8]);
      const bf16_t* wb2 = wbuf + 24576 + f * 2048;
#pragma unroll
      for (int nt = 0; nt < 4; ++nt) {
        const bf16x8 bfv = *(const bf16x8*)(wb2 + (nt * 64 + lane) * 8);
        acc2[nt] = __builtin_amdgcn_mfma_f32_16x16x32_bf16(a2, bfv, acc2[nt], 0, 0, 0);
      }
    }
  }

  // ---- Final: + bn2, * mask, store ----
  int mm[4];
#pragma unroll
  for (int r = 0; r < 4; ++r) mm[r] = mask[nodebase + q * 4 + r];
#pragma unroll
  for (int nt = 0; nt < 4; ++nt) {
    const float bv = bn2[nt * 16 + e];
#pragma unroll
    for (int r = 0; r < 4; ++r) {
      const int node = nodebase + q * 4 + r;
      out[(size_t)node * 64 + nt * 16 + e] = (acc2[nt][r] + bv) * (float)mm[r];
    }
  }
}

// ---------------- Launch ----------------
extern "C" void kernel_launch(void* const* d_in, const int* in_sizes, int n_in,
                              void* d_out, int out_size, void* d_ws, size_t ws_size,
                              hipStream_t stream) {
  const float* nodes = (const float*)d_in[0];
  const int*   mask  = (const int*)d_in[1];
  const float* We1   = (const float*)d_in[2];
  const float* be1   = (const float*)d_in[3];
  const float* We2   = (const float*)d_in[4];
  const float* be2   = (const float*)d_in[5];
  const float* Wn1   = (const float*)d_in[6];
  const float* bn1   = (const float*)d_in[7];
  const float* Wn2   = (const float*)d_in[8];
  const float* bn2   = (const float*)d_in[9];
  float* out = (float*)d_out;

  char* p = (char*)d_ws;
  auto alloc = [&](size_t bytes) -> char* {
    char* r = p;
    p += (bytes + 255) & ~(size_t)255;
    return r;
  };
  bf16_t* xhi    = (bf16_t*)alloc((size_t)32768 * 64 * 2);
  bf16_t* xlo    = (bf16_t*)alloc((size_t)32768 * 64 * 2);
  float*  sq     = (float*)alloc((size_t)32768 * 4);
  int*    vlist  = (int*)alloc((size_t)32768 * 4);
  int*    vcnt   = (int*)alloc((size_t)64 * 4);
  int*    idxg   = (int*)alloc((size_t)32768 * 16 * 4);
  float*  pooled = (float*)alloc((size_t)32768 * 128 * 4);
  bf16_t* W1p    = (bf16_t*)alloc((size_t)8 * 8 * 64 * 8 * 2);
  bf16_t* W2p    = (bf16_t*)alloc((size_t)8 * 8 * 64 * 8 * 2);
  bf16_t* Wn1p   = (bf16_t*)alloc((size_t)12 * 8 * 64 * 8 * 2);
  bf16_t* Wn2p   = (bf16_t*)alloc((size_t)8 * 4 * 64 * 8 * 2);
  if ((size_t)(p - (char*)d_ws) > ws_size) return;  // workspace too small -> loud failure

  kfuse<<<640, 256, 0, stream>>>(nodes, mask, We1, We2, Wn1, Wn2,
                                 xhi, xlo, sq, vlist, vcnt, W1p, W2p, Wn1p, Wn2p);
  kknn<<<2048, 256, 0, stream>>>(xhi, xlo, sq, vlist, vcnt, idxg);
  kedge<<<512, 256, 0, stream>>>(xhi, xlo, idxg, vlist, vcnt, W1p, W2p, be1, be2, pooled);
  knode<<<512, 256, 0, stream>>>(xhi, xlo, pooled, mask, Wn1p, Wn2p, bn1, bn2, out);
}

// Round 14
// 151.553 us; speedup vs baseline: 1.1635x; 1.0181x over previous
//
#include <hip/hip_runtime.h>

#define DI __device__ __forceinline__

typedef __bf16 bf16_t;
typedef __bf16 bf16x4 __attribute__((ext_vector_type(4)));
typedef __bf16 bf16x8 __attribute__((ext_vector_type(8)));
typedef float f32x4 __attribute__((ext_vector_type(4)));
typedef unsigned long long u64;

// Problem constants
// B=64, N=512, F=64, H=128, FO=64, K=16

DI bf16_t f2b(float f) {
  unsigned u = __float_as_uint(f);
  unsigned r = (u + 0x7fffu + ((u >> 16) & 1u)) >> 16;
  return __builtin_bit_cast(bf16_t, (unsigned short)r);
}
DI float b2f(bf16_t h) {
  return __uint_as_float(((unsigned)__builtin_bit_cast(unsigned short, h)) << 16);
}
DI f32x4 zero4() { f32x4 z = {0.f, 0.f, 0.f, 0.f}; return z; }

// Both planes from one f32 load (knode L1, pooled region).
DI void make_frag2(const float* p, bf16x8* hi, bf16x8* lo) {
  float4 v0 = *(const float4*)p;
  float4 v1 = *(const float4*)(p + 4);
  float vv[8] = {v0.x, v0.y, v0.z, v0.w, v1.x, v1.y, v1.z, v1.w};
#pragma unroll
  for (int j = 0; j < 8; ++j) {
    bf16_t h = f2b(vv[j]);
    (*hi)[j] = h;
    (*lo)[j] = f2b(vv[j] - b2f(h));
  }
}

DI u64 u64min(u64 a, u64 b) { return a < b ? a : b; }
// ctrl must be an ICE for __builtin_amdgcn_update_dpp -> template parameter.
template <int CTRL>
DI u64 dpp_u64(u64 v) {
  int lo = (int)(unsigned)(v & 0xffffffffull);
  int hi = (int)(unsigned)(v >> 32);
  int tlo = __builtin_amdgcn_update_dpp(0, lo, CTRL, 0xF, 0xF, true);
  int thi = __builtin_amdgcn_update_dpp(0, hi, CTRL, 0xF, 0xF, true);
  return (((u64)(unsigned)thi) << 32) | (unsigned)tlo;
}
template <int CTRL>
DI float dpp_f32(float v) {
  int t = __builtin_amdgcn_update_dpp(0, (int)__float_as_uint(v), CTRL, 0xF, 0xF, true);
  return __uint_as_float((unsigned)t);
}
// Min over each 16-lane row; result uniform within the row.
DI u64 rowmin_u64(u64 v) {
  v = u64min(v, dpp_u64<0xB1>(v));
  v = u64min(v, dpp_u64<0x4E>(v));
  v = u64min(v, dpp_u64<0x141>(v));
  v = u64min(v, dpp_u64<0x140>(v));
  return v;
}
// Sum over each 16-lane row (butterfly); result uniform within the row.
DI float rowsum_f32(float v) {
  v += dpp_f32<0xB1>(v);
  v += dpp_f32<0x4E>(v);
  v += dpp_f32<0x141>(v);
  v += dpp_f32<0x140>(v);
  return v;
}
// Bitonic sort, 16 elements, ascending. 80 CAS, all indices compile-time.
DI void bitonic16(u64* a) {
#pragma unroll
  for (int k = 2; k <= 16; k <<= 1)
#pragma unroll
    for (int j = k >> 1; j > 0; j >>= 1)
#pragma unroll
      for (int i = 0; i < 16; ++i) {
        const int l = i ^ j;
        if (l > i) {
          const bool up = ((i & k) == 0);
          const bool sw = up ? (a[i] > a[l]) : (a[i] < a[l]);
          const u64 t0 = a[i], t1 = a[l];
          a[i] = sw ? t1 : t0;
          a[l] = sw ? t0 : t1;
        }
      }
}
// Insert k into ascending sorted a[16], dropping the max. INF insert = no-op.
DI void sorted_insert16(u64* a, u64 k) {
  u64 na[16];
#pragma unroll
  for (int p = 0; p < 16; ++p) {
    const bool cur_gt = (a[p] > k);
    const bool prv_le = (p == 0) ? true : (a[p - 1] <= k);
    na[p] = !cur_gt ? a[p] : (prv_le ? k : a[p - 1]);
  }
#pragma unroll
  for (int p = 0; p < 16; ++p) a[p] = na[p];
}

// ---------------- Kernel F: fused prep — xplanes (512) + compact (64) + pack (64) --
__global__ void __launch_bounds__(256) kfuse(const float* __restrict__ nodes,
    const int* __restrict__ mask,
    const float* __restrict__ We1, const float* __restrict__ We2,
    const float* __restrict__ Wn1, const float* __restrict__ Wn2,
    bf16_t* __restrict__ xhi, bf16_t* __restrict__ xlo,
    float* __restrict__ sq, int* __restrict__ vlist, int* __restrict__ vcnt,
    bf16_t* __restrict__ W1p, bf16_t* __restrict__ W2p,
    bf16_t* __restrict__ Wn1p, bf16_t* __restrict__ Wn2p) {
  const int blk = blockIdx.x, t = threadIdx.x;
  __shared__ int cnts[8];
  __shared__ int basep[8];

  if (blk < 512) {
    // ---- xplanes: batch b, nodes n0..n0+63; 16 threads per row ----
    const int b = blk >> 3, n0 = (blk & 7) * 64;
#pragma unroll
    for (int i = 0; i < 4; ++i) {
      const int idx = t + 256 * i;
      const int gi = b * 512 + n0 + (idx >> 4);
      const int fo = (idx & 15) * 4;
      const float fm = (float)mask[gi];
      const size_t ro = (size_t)gi * 64;
      float4 v = *(const float4*)(nodes + ro + fo);
      v.x *= fm; v.y *= fm; v.z *= fm; v.w *= fm;
      float vv[4] = {v.x, v.y, v.z, v.w};
      bf16x4 hh, ll;
#pragma unroll
      for (int k = 0; k < 4; ++k) {
        bf16_t hi = f2b(vv[k]);
        hh[k] = hi;
        ll[k] = f2b(vv[k] - b2f(hi));
      }
      *(bf16x4*)(xhi + ro + fo) = hh;
      *(bf16x4*)(xlo + ro + fo) = ll;
      float s = v.x * v.x + v.y * v.y + v.z * v.z + v.w * v.w;
      s = rowsum_f32(s);  // sum over the row's 16 lanes (uniform in row)
      if ((t & 15) == 0) sq[gi] = s;
    }
  } else if (blk < 576) {
    // ---- compaction: one block per batch ----
    const int b = blk - 512, lane = t & 63, w = t >> 6;
    unsigned long long bal[2]; int flag[2];
#pragma unroll
    for (int h = 0; h < 2; ++h) {
      flag[h] = (mask[b * 512 + h * 256 + t] != 0);
      bal[h] = __ballot(flag[h]);
      if (lane == 0) cnts[h * 4 + w] = __popcll(bal[h]);
    }
    __syncthreads();
    if (t == 0) {
      int a = 0;
      for (int c = 0; c < 8; ++c) { basep[c] = a; a += cnts[c]; }
      vcnt[b] = a;
    }
    __syncthreads();
#pragma unroll
    for (int h = 0; h < 2; ++h) {
      if (flag[h]) {
        const unsigned long long lt = (lane == 0) ? 0ull : (~0ull >> (64 - lane));
        const int pos = basep[h * 4 + w] + __popcll(bal[h] & lt);
        vlist[b * 512 + pos] = h * 256 + t;
      }
    }
  } else {
    // ---- weight pack ----
    int p = (blk - 576) * 256 + t;  // 0..16383
    const float* W; bf16_t* dst; int K, Nn, local, mode;
    if (p < 4096)       { W = We1; dst = W1p;  K = 128; Nn = 128; mode = 0; local = p; }
    else if (p < 8192)  { W = We2; dst = W2p;  K = 128; Nn = 128; mode = 1; local = p - 4096; }
    else if (p < 14336) { W = Wn1; dst = Wn1p; K = 192; Nn = 128; mode = 0; local = p - 8192; }
    else                { W = Wn2; dst = Wn2p; K = 128; Nn = 64;  mode = 1; local = p - 14336; }
    int lane = local & 63;
    int nnt = (Nn >> 4);
    int chunk = local >> 6;
    int nt = chunk % nnt;
    int s = chunk / nnt;
    int n = nt * 16 + (lane & 15);
    int kbase = s * 32 + ((lane >> 4) * 8);
    bf16x8 v;
#pragma unroll
    for (int j = 0; j < 8; ++j) {
      int kp = kbase + j;
      int region = kp / K;
      int kk = kp - region * K;
      float w = W[kk * Nn + n];
      bf16_t hi = f2b(w);
      v[j] = (mode == 1 && region == 1) ? f2b(w - b2f(hi)) : hi;
    }
    *(bf16x8*)(dst + (size_t)local * 8) = v;
  }
}

// ---------------- Kernel B: kknn (blocks <2048) + krecv role (blocks 2048..2559) --
// krecv computes recvpart[node][128] = x[node]·W1top via the EXACT MFMA sequence of
// kedge's old receiver phase (slabs 0,1; per nt: hi then lo) -> kedge can C-init
// with recvpart and skip the receiver half, BIT-IDENTICAL (MFMA rows independent;
// C-chaining init == running the recv MFMAs first). The 512 krecv blocks fill CUs
// vacated by kknn's ~1000 early-exit blocks (same deps: xhi/xlo/W1p after kfuse).
// Shared mem aliased: kknn uses 37376 B (sqs|vls|S), krecv uses first 16384 B.
__global__ void __launch_bounds__(256) kknn(const bf16_t* __restrict__ xhi,
    const bf16_t* __restrict__ xlo,
    const float* __restrict__ sq, const int* __restrict__ vlist,
    const int* __restrict__ vcnt, int* __restrict__ idxg,
    const bf16_t* __restrict__ W1p, float* __restrict__ recvpart) {
  __shared__ __align__(16) unsigned char smem[37376];
  const int t = threadIdx.x, lane = t & 63, w = t >> 6;
  const int i = lane >> 4, d = lane & 15;
  const int q = i, e = d;  // aliases for the krecv role

  if (blockIdx.x >= 2048) {
    // ---------------- krecv role ----------------
    const int blk2 = blockIdx.x - 2048;          // 0..511
    bf16_t* wbuf = (bf16_t*)smem;                // 16 KB: W1 slabs 0-1
    {
      const uint4* s1 = (const uint4*)W1p;
      uint4* dst = (uint4*)wbuf;
#pragma unroll
      for (int k = 0; k < 4; ++k) dst[t + 256 * k] = s1[t + 256 * k];
    }
    __syncthreads();
    const int nodebase = (blk2 * 4 + w) * 16;
    f32x4 acc[8];
#pragma unroll
    for (int nt = 0; nt < 8; ++nt) acc[nt] = zero4();
#pragma unroll
    for (int inner = 0; inner < 2; ++inner) {
      const int off = inner * 32 + q * 8;
      const int node = nodebase + e;
      const bf16x8 h = *(const bf16x8*)(xhi + (size_t)node * 64 + off);
      const bf16x8 l = *(const bf16x8*)(xlo + (size_t)node * 64 + off);
#pragma unroll
      for (int nt = 0; nt < 8; ++nt) {
        const bf16x8 bfv = *(const bf16x8*)(wbuf + inner * 4096 + (nt * 64 + lane) * 8);
        acc[nt] = __builtin_amdgcn_mfma_f32_16x16x32_bf16(h, bfv, acc[nt], 0, 0, 0);
        acc[nt] = __builtin_amdgcn_mfma_f32_16x16x32_bf16(l, bfv, acc[nt], 0, 0, 0);
      }
    }
#pragma unroll
    for (int nt = 0; nt < 8; ++nt)
#pragma unroll
      for (int r = 0; r < 4; ++r)
        recvpart[(size_t)(nodebase + q * 4 + r) * 128 + nt * 16 + e] = acc[nt][r];
    return;
  }

  // ---------------- kknn role (unchanged machinery) ----------------
  const int b = blockIdx.x & 63, tile = blockIdx.x >> 6;
  const int nv = vcnt[b];
  if (tile * 16 >= nv) return;  // block-uniform, before any barrier
  float* sqs = (float*)smem;                 // 2048 B
  int* vls = (int*)(smem + 2048);            // 2048 B
  float* S = (float*)(smem + 4096);          // 16*520*4 = 33280 B
  for (int k = t; k < 512; k += 256) { sqs[k] = sq[b * 512 + k]; vls[k] = vlist[b * 512 + k]; }
  __syncthreads();

  const size_t xb = (size_t)b * 512 * 64;

  const int aslot = tile * 16 + d;
  const int arow = vls[aslot < nv ? aslot : 0];
  bf16x8 ah[2], al[2];
#pragma unroll
  for (int kh = 0; kh < 2; ++kh) {
    ah[kh] = *(const bf16x8*)(xhi + xb + (size_t)arow * 64 + kh * 32 + i * 8);
    al[kh] = *(const bf16x8*)(xlo + xb + (size_t)arow * 64 + kh * 32 + i * 8);
  }

  const int rslot = tile * 16 + w * 4 + i;
  const bool vrow = (rslot < nv);
  const int nrow = vls[rslot < nv ? rslot : 0];
  const float sqn = sqs[nrow];

  int crs[8];
#pragma unroll
  for (int jj = 0; jj < 8; ++jj) {
    const int c = (w + 4 * jj) * 16 + d;
    crs[jj] = vls[c < nv ? c : 0];
  }

  bf16x8 pbh[4][2], pbl[4][2];
#pragma unroll
  for (int jj = 0; jj < 4; ++jj) {
    if ((w + 4 * jj) * 16 < nv) {  // wave-uniform
#pragma unroll
      for (int kh = 0; kh < 2; ++kh) {
        pbh[jj][kh] = *(const bf16x8*)(xhi + xb + (size_t)crs[jj] * 64 + kh * 32 + i * 8);
        pbl[jj][kh] = *(const bf16x8*)(xlo + xb + (size_t)crs[jj] * 64 + kh * 32 + i * 8);
      }
    }
  }
#pragma unroll
  for (int jj = 0; jj < 8; ++jj) {
    const int ct = w + 4 * jj;
    if (ct * 16 < nv) {  // wave-uniform
      const int sl = jj & 3;
      bf16x8 bh[2] = {pbh[sl][0], pbh[sl][1]};
      bf16x8 bl[2] = {pbl[sl][0], pbl[sl][1]};
      if (jj < 4 && (w + 4 * (jj + 4)) * 16 < nv) {
#pragma unroll
        for (int kh = 0; kh < 2; ++kh) {
          pbh[sl][kh] = *(const bf16x8*)(xhi + xb + (size_t)crs[jj + 4] * 64 + kh * 32 + i * 8);
          pbl[sl][kh] = *(const bf16x8*)(xlo + xb + (size_t)crs[jj + 4] * 64 + kh * 32 + i * 8);
        }
      }
      f32x4 acc = zero4();
#pragma unroll
      for (int kh = 0; kh < 2; ++kh) {
        acc = __builtin_amdgcn_mfma_f32_16x16x32_bf16(ah[kh], bh[kh], acc, 0, 0, 0);
        acc = __builtin_amdgcn_mfma_f32_16x16x32_bf16(ah[kh], bl[kh], acc, 0, 0, 0);
        acc = __builtin_amdgcn_mfma_f32_16x16x32_bf16(al[kh], bh[kh], acc, 0, 0, 0);
        acc = __builtin_amdgcn_mfma_f32_16x16x32_bf16(al[kh], bl[kh], acc, 0, 0, 0);
      }
#pragma unroll
      for (int r = 0; r < 4; ++r) S[(i * 4 + r) * 520 + ct * 16 + d] = acc[r];
    }
  }
  __syncthreads();

  const u64 INF64 = ~0ull;
  u64 s1[16];
#pragma unroll
  for (int j = 0; j < 16; ++j) s1[j] = INF64;
#pragma unroll
  for (int j = 0; j < 16; ++j) {
    if (j * 16 < nv) {  // uniform
      const int c = j * 16 + d;
      const int m = vls[c < nv ? c : 0];
      const float dot = S[(w * 4 + i) * 520 + j * 16 + d];
      const float dd = fabsf(sqn + sqs[m] - 2.f * dot);
      const u64 key = (((u64)__float_as_uint(dd)) << 32) | (unsigned)m;
      const bool ok = (c < nv) && (m != nrow);
      s1[j] = ok ? key : INF64;
    }
  }
  bitonic16(s1);
  for (int j = 16; j * 16 < nv; ++j) {
    const int c = j * 16 + d;
    const int m = vls[c < nv ? c : 0];
    const float dot = S[(w * 4 + i) * 520 + j * 16 + d];
    const float dd = fabsf(sqn + sqs[m] - 2.f * dot);
    const u64 key = (((u64)__float_as_uint(dd)) << 32) | (unsigned)m;
    const bool ok = (c < nv) && (m != nrow);
    sorted_insert16(s1, ok ? key : INF64);
  }

  int res = nrow;
#pragma unroll
  for (int ts = 0; ts < 16; ++ts) {
    const u64 wmin = rowmin_u64(s1[0]);
    if (d == ts) res = (wmin == INF64) ? nrow : (int)(unsigned)(wmin & 0xffffffffull);
    const bool w1 = (wmin != INF64) && (s1[0] == wmin);
#pragma unroll
    for (int k = 0; k < 15; ++k) s1[k] = w1 ? s1[k + 1] : s1[k];
    s1[15] = w1 ? INF64 : s1[15];
  }
  if (vrow) idxg[((size_t)b * 512 + rslot) * 16 + d] = res;
}

// ---------------- Kernel C: edge MLP — sender-only L1 + recvpart C-init -----------
// Receiver half of L1 factored out (krecv): acc C-init = recvpart (bit-identical to
// running the receiver MFMAs first). Per pair-iter: MFMA 192->128, gathers 16->8,
// W1 LDS 32->16 KB (total LDS 64+16=80... now 48+16=64 KB), fewer live VGPRs.
__global__ void __launch_bounds__(256, 2) kedge(const bf16_t* __restrict__ xhi,
    const bf16_t* __restrict__ xlo, const float* __restrict__ recvpart,
    const int* __restrict__ idxg, const int* __restrict__ vlist,
    const int* __restrict__ vcnt,
    const bf16_t* __restrict__ W1p, const bf16_t* __restrict__ W2p,
    const float* __restrict__ be1, const float* __restrict__ be2,
    float* __restrict__ pooled) {
  __shared__ __align__(16) bf16_t wbuf[24576];       // 48 KB: W1 slabs2-3 | W2 slabs0-3
  __shared__ __align__(16) bf16_t hfrag[4][2][1024]; // 16 KB
  const int t = threadIdx.x, lane = t & 63, w = t >> 6;
  const int q = lane >> 4, e = lane & 15;
  const int bb = blockIdx.x & 63;              // same-XCD batch grouping
  const int s0 = ((blockIdx.x >> 6) * 4 + w) * 2;  // even slot base 0..62

  // ---- stage W1 slabs 2-3 (16 KB) + W2 (32 KB) ----
  {
    const uint4* s1 = (const uint4*)(W1p + 8192);  // slabs 2-3
    const uint4* s2 = (const uint4*)W2p;
    uint4* dst = (uint4*)wbuf;
#pragma unroll
    for (int i = 0; i < 4; ++i) dst[t + 256 * i] = s1[t + 256 * i];
#pragma unroll
    for (int i = 0; i < 8; ++i) dst[1024 + t + 256 * i] = s2[t + 256 * i];
  }
  __syncthreads();  // the ONLY barrier in this kernel

  const int nv = vcnt[bb];
  if (s0 >= nv) return;

  int vl[2], sv[2];
#pragma unroll
  for (int u = 0; u < 2; ++u) {
    const int sl = (s0 + u) < nv ? (s0 + u) : 0;
    vl[u] = vlist[bb * 512 + sl];
    sv[u] = idxg[((size_t)(bb * 512 + sl) << 4) + e];
  }

  for (int base = s0; base < nv; base += 64) {
    const bool act1 = (base + 1) < nv;
    const int gid0 = bb * 512 + vl[0];
    const int gid1 = bb * 512 + vl[1];
    const size_t nb0 = (size_t)(bb * 512 + sv[0]) << 6;
    const size_t nb1 = (size_t)(bb * 512 + sv[1]) << 6;

    // ---- sender A-frags: af[u][k] k<2 = hi(inner k), k>=2 = lo(inner k-2) ----
    bf16x8 af[2][4];
#pragma unroll
    for (int k = 0; k < 2; ++k) {
      const int off = k * 32 + q * 8;
      af[0][k]     = *(const bf16x8*)(xhi + nb0 + off);
      af[1][k]     = *(const bf16x8*)(xhi + nb1 + off);
      af[0][2 + k] = *(const bf16x8*)(xlo + nb0 + off);
      af[1][2 + k] = *(const bf16x8*)(xlo + nb1 + off);
    }

    // ---- acc C-init from recvpart (== receiver MFMA partial, bit-identical) ----
    f32x4 acc[2][8];
#pragma unroll
    for (int u = 0; u < 2; ++u) {
      const int gid = u ? gid1 : gid0;
#pragma unroll
      for (int nt = 0; nt < 8; ++nt) {
        const float rv = recvpart[(size_t)gid * 128 + nt * 16 + e];
        f32x4 v = {rv, rv, rv, rv};
        acc[u][nt] = v;
      }
    }

    // ---- prefetch next slot pair's indices (1-deep) ----
    int nvl[2] = {vl[0], vl[1]}, nsv[2] = {sv[0], sv[1]};
    {
      const int nbs = base + 64;
      if (nbs < nv) {
#pragma unroll
        for (int u = 0; u < 2; ++u) {
          const int sl = (nbs + u) < nv ? (nbs + u) : 0;
          nvl[u] = vlist[bb * 512 + sl];
          nsv[u] = idxg[((size_t)(bb * 512 + sl) << 4) + e];
        }
      }
    }

    // ---- Layer 1 (sender half only): slabs 2+inner at wbuf + inner*4096 ----
#pragma unroll
    for (int inner = 0; inner < 2; ++inner) {
      const bf16_t* wb = wbuf + inner * 4096;
      const bf16x8 h0 = af[0][inner];
      const bf16x8 h1 = af[1][inner];
      const bf16x8 l0 = af[0][2 + inner];
      const bf16x8 l1 = af[1][2 + inner];
#pragma unroll
      for (int nt = 0; nt < 8; ++nt) {
        const bf16x8 bfv = *(const bf16x8*)(wb + (nt * 64 + lane) * 8);
        acc[0][nt] = __builtin_amdgcn_mfma_f32_16x16x32_bf16(h0, bfv, acc[0][nt], 0, 0, 0);
        acc[0][nt] = __builtin_amdgcn_mfma_f32_16x16x32_bf16(l0, bfv, acc[0][nt], 0, 0, 0);
        acc[1][nt] = __builtin_amdgcn_mfma_f32_16x16x32_bf16(h1, bfv, acc[1][nt], 0, 0, 0);
        acc[1][nt] = __builtin_amdgcn_mfma_f32_16x16x32_bf16(l1, bfv, acc[1][nt], 0, 0, 0);
      }
    }

    // ---- L2 in two halves interleaved with epilogue-1 (same FP order) ----
    f32x4 acc2[2][8];
#pragma unroll
    for (int u = 0; u < 2; ++u)
#pragma unroll
      for (int nt = 0; nt < 8; ++nt) acc2[u][nt] = zero4();

#pragma unroll
    for (int hh = 0; hh < 2; ++hh) {
#pragma unroll
      for (int u = 0; u < 2; ++u)
#pragma unroll
        for (int nt4 = 0; nt4 < 4; ++nt4) {
          const int nt = hh * 4 + nt4;
          const int cc = nt * 16 + e;
          const float bv = be1[cc];
          const int bse = (((cc >> 5) & 1) * 64 + q * 4 + 16 * ((cc >> 3) & 3)) * 8 + (cc & 7);
#pragma unroll
          for (int r = 0; r < 4; ++r)
            hfrag[w][u][bse + r * 8] = f2b(fmaxf(acc[u][nt][r] + bv, 0.f));
        }
      // L2 half: W2 hi slabs f = hh*2, hh*2+1 (wbuf offset 8192)
#pragma unroll
      for (int sl = 0; sl < 2; ++sl) {
        const int f = hh * 2 + sl;
        const bf16x8 a20 = *(const bf16x8*)(&hfrag[w][0][(sl * 64 + lane) * 8]);
        const bf16x8 a21 = *(const bf16x8*)(&hfrag[w][1][(sl * 64 + lane) * 8]);
        const bf16_t* wb2 = wbuf + 8192 + f * 4096;
#pragma unroll
        for (int nt = 0; nt < 8; ++nt) {
          const bf16x8 bfv = *(const bf16x8*)(wb2 + (nt * 64 + lane) * 8);
          acc2[0][nt] = __builtin_amdgcn_mfma_f32_16x16x32_bf16(a20, bfv, acc2[0][nt], 0, 0, 0);
          acc2[1][nt] = __builtin_amdgcn_mfma_f32_16x16x32_bf16(a21, bfv, acc2[1][nt], 0, 0, 0);
        }
      }
    }

    // ---- Epilogue 2: bias+relu, mean over 16 edges (cnt==16 exactly) ----
#pragma unroll
    for (int u = 0; u < 2; ++u) {
      if (u == 0 || act1) {
        const int gid = u ? gid1 : gid0;
#pragma unroll
        for (int nt = 0; nt < 8; ++nt) {
          const float bv = be2[nt * 16 + e];
          float part = 0.f;
#pragma unroll
          for (int r = 0; r < 4; ++r) part += fmaxf(acc2[u][nt][r] + bv, 0.f);
          part += __shfl_xor(part, 16, 64);
          part += __shfl_xor(part, 32, 64);
          if (lane < 16) pooled[(size_t)gid * 128 + nt * 16 + lane] = part * 0.0625f;
        }
      }
    }

    vl[0] = nvl[0]; vl[1] = nvl[1];
    sv[0] = nsv[0]; sv[1] = nsv[1];
  }
}

// ---------------- Kernel D: node MLP — persistent-weight, planes-direct L1 --------
__global__ void __launch_bounds__(256, 2) knode(const bf16_t* __restrict__ xhi,
    const bf16_t* __restrict__ xlo,
    const float* __restrict__ pooled, const int* __restrict__ mask,
    const bf16_t* __restrict__ Wn1p, const bf16_t* __restrict__ Wn2p,
    const float* __restrict__ bn1, const float* __restrict__ bn2,
    float* __restrict__ out) {
  __shared__ __align__(16) bf16_t wbuf[32768];     // 64 KB: Wn1 slabs0-5 | Wn2 slabs0-3
  __shared__ __align__(16) bf16_t hfrag[4][1024];  // 8 KB (half-H per wave)
  const int t = threadIdx.x, lane = t & 63, w = t >> 6;
  const int q = lane >> 4, e = lane & 15;
  const int nodebase = (blockIdx.x * 4 + w) * 16;

  {
    const uint4* s1 = (const uint4*)Wn1p;          // slabs 0-5 = first 48 KB
    const uint4* s2 = (const uint4*)Wn2p;          // slabs 0-3 = first 16 KB
    uint4* dst = (uint4*)wbuf;
#pragma unroll
    for (int i = 0; i < 12; ++i) dst[t + 256 * i] = s1[t + 256 * i];
#pragma unroll
    for (int i = 0; i < 4; ++i) dst[3072 + t + 256 * i] = s2[t + 256 * i];
  }
  __syncthreads();  // the ONLY barrier in this kernel

  f32x4 acc[8];
#pragma unroll
  for (int nt = 0; nt < 8; ++nt) acc[nt] = zero4();

#pragma unroll
  for (int sr = 0; sr < 6; ++sr) {
    const int col = sr * 32 + q * 8;  // [0,192)
    const int node = nodebase + e;
    bf16x8 afh, afl;
    if (sr < 2) {  // x region: planes direct (bit-identical)
      afh = *(const bf16x8*)(xhi + (size_t)node * 64 + col);
      afl = *(const bf16x8*)(xlo + (size_t)node * 64 + col);
    } else {       // pooled region
      make_frag2(pooled + (size_t)node * 128 + (col - 64), &afh, &afl);
    }
#pragma unroll
    for (int nt = 0; nt < 8; ++nt) {
      const bf16x8 bfv = *(const bf16x8*)(wbuf + sr * 4096 + (nt * 64 + lane) * 8);
      acc[nt] = __builtin_amdgcn_mfma_f32_16x16x32_bf16(afh, bfv, acc[nt], 0, 0, 0);
      acc[nt] = __builtin_amdgcn_mfma_f32_16x16x32_bf16(afl, bfv, acc[nt], 0, 0, 0);
    }
  }

  f32x4 acc2[4];
#pragma unroll
  for (int nt = 0; nt < 4; ++nt) acc2[nt] = zero4();

#pragma unroll
  for (int hh = 0; hh < 2; ++hh) {
#pragma unroll
    for (int nt4 = 0; nt4 < 4; ++nt4) {
      const int nt = hh * 4 + nt4;
      const int cc = nt * 16 + e;
      const float bv = bn1[cc];
      const int bse = (((cc >> 5) & 1) * 64 + q * 4 + 16 * ((cc >> 3) & 3)) * 8 + (cc & 7);
#pragma unroll
      for (int r = 0; r < 4; ++r)
        hfrag[w][bse + r * 8] = f2b(fmaxf(acc[nt][r] + bv, 0.f));
    }
#pragma unroll
    for (int sl = 0; sl < 2; ++sl) {
      const int f = hh * 2 + sl;
      const bf16x8 a2 = *(const bf16x8*)(&hfrag[w][(sl * 64 + lane) * 8]);
      const bf16_t* wb2 = wbuf + 24576 + f * 2048;
#pragma unroll
      for (int nt = 0; nt < 4; ++nt) {
        const bf16x8 bfv = *(const bf16x8*)(wb2 + (nt * 64 + lane) * 8);
        acc2[nt] = __builtin_amdgcn_mfma_f32_16x16x32_bf16(a2, bfv, acc2[nt], 0, 0, 0);
      }
    }
  }

  int mm[4];
#pragma unroll
  for (int r = 0; r < 4; ++r) mm[r] = mask[nodebase + q * 4 + r];
#pragma unroll
  for (int nt = 0; nt < 4; ++nt) {
    const float bv = bn2[nt * 16 + e];
#pragma unroll
    for (int r = 0; r < 4; ++r) {
      const int node = nodebase + q * 4 + r;
      out[(size_t)node * 64 + nt * 16 + e] = (acc2[nt][r] + bv) * (float)mm[r];
    }
  }
}

// ---------------- Launch ----------------
extern "C" void kernel_launch(void* const* d_in, const int* in_sizes, int n_in,
                              void* d_out, int out_size, void* d_ws, size_t ws_size,
                              hipStream_t stream) {
  const float* nodes = (const float*)d_in[0];
  const int*   mask  = (const int*)d_in[1];
  const float* We1   = (const float*)d_in[2];
  const float* be1   = (const float*)d_in[3];
  const float* We2   = (const float*)d_in[4];
  const float* be2   = (const float*)d_in[5];
  const float* Wn1   = (const float*)d_in[6];
  const float* bn1   = (const float*)d_in[7];
  const float* Wn2   = (const float*)d_in[8];
  const float* bn2   = (const float*)d_in[9];
  float* out = (float*)d_out;

  char* p = (char*)d_ws;
  auto alloc = [&](size_t bytes) -> char* {
    char* r = p;
    p += (bytes + 255) & ~(size_t)255;
    return r;
  };
  bf16_t* xhi      = (bf16_t*)alloc((size_t)32768 * 64 * 2);
  bf16_t* xlo      = (bf16_t*)alloc((size_t)32768 * 64 * 2);
  float*  sq       = (float*)alloc((size_t)32768 * 4);
  int*    vlist    = (int*)alloc((size_t)32768 * 4);
  int*    vcnt     = (int*)alloc((size_t)64 * 4);
  int*    idxg     = (int*)alloc((size_t)32768 * 16 * 4);
  float*  pooled   = (float*)alloc((size_t)32768 * 128 * 4);
  float*  recvpart = (float*)alloc((size_t)32768 * 128 * 4);
  bf16_t* W1p      = (bf16_t*)alloc((size_t)8 * 8 * 64 * 8 * 2);
  bf16_t* W2p      = (bf16_t*)alloc((size_t)8 * 8 * 64 * 8 * 2);
  bf16_t* Wn1p     = (bf16_t*)alloc((size_t)12 * 8 * 64 * 8 * 2);
  bf16_t* Wn2p     = (bf16_t*)alloc((size_t)8 * 4 * 64 * 8 * 2);
  if ((size_t)(p - (char*)d_ws) > ws_size) return;  // workspace too small -> loud failure

  kfuse<<<640, 256, 0, stream>>>(nodes, mask, We1, We2, Wn1, Wn2,
                                 xhi, xlo, sq, vlist, vcnt, W1p, W2p, Wn1p, Wn2p);
  kknn<<<2560, 256, 0, stream>>>(xhi, xlo, sq, vlist, vcnt, idxg, W1p, recvpart);
  kedge<<<512, 256, 0, stream>>>(xhi, xlo, recvpart, idxg, vlist, vcnt,
                                 W1p, W2p, be1, be2, pooled);
  knode<<<512, 256, 0, stream>>>(xhi, xlo, pooled, mask, Wn1p, Wn2p, bn1, bn2, out);
}